// Round 8
// baseline (1771.208 us; speedup 1.0000x reference)
//
#include <hip/hip_runtime.h>
#include <stdint.h>

// MinkFormerBlock on MI355X (gfx950). ALL I/O IS F32 (inputs f32 per R3's
// NaN proof; OUTPUT F32 per the R0-R7 signature: writing 4.2M u16 into a
// 4.2M-float d_out leaves the upper 8MB zero -> err == ref_absmax exactly,
// deterministic across rounds. The "(bf16" in the test label is a hard-coded
// template literal, not a dtype indicator).
//
// Internals: bf16 activations/weights + MFMA 16x16x32 (f32 accumulate).
//   wt_all:    WT* = bf16(W^T)  [tap][Cout][Cin]
//   gg<1,0>:   a = x @ Wa1      (f32 src staged->bf16, bf16 out)
//   gg<1,0>:   v = x @ Wv1
//   gg<125,1>: g = gather(a,nbr5)@W5 * v    (bf16, fused gate)
//   gg<27,2>:  t = gather(g,nbr3a)@W31      (f32, overlays a|v)
//   bn + fin -> sc1,sh1
//   ew1:       o = t*sc+sh + x; res=bf16(o)->gbuf; h=bf16(relu o)->hbuf
//   gg<27,2>:  t2 = gather(h,nbr3b)@W32     (f32, overlays a|v)
//   bn + fin -> sc2,sh2
//   ew2:       d_out[i] = relu(t2*sc2+sh2 + res)   (F32 WRITES)
// Instrumentation kept 1 more round: sentinel fill, stage checkers (codes
// 1100 a / 1200 g / 1300 h / 1500,1600 BN), contract codes 5900/4000+/2000+.

#define NPTS 32768
#define C 128
#define EPS 1e-5f

typedef unsigned short u16;
using bfrag = __attribute__((ext_vector_type(8))) short;   // 8 bf16 = 4 VGPRs
using f32x4 = __attribute__((ext_vector_type(4))) float;

__device__ __forceinline__ float b2f(u16 u) {
  union { unsigned int i; float f; } x;
  x.i = ((unsigned int)u) << 16;
  return x.f;
}
__device__ __forceinline__ u16 f2b(float f) {
  union { float f; unsigned int i; } x;
  x.f = f;
  unsigned int r = x.i + 0x7FFFu + ((x.i >> 16) & 1u);   // RNE
  return (u16)(r >> 16);
}
__device__ __forceinline__ unsigned int pack2(float lo, float hi) {
  return (unsigned int)f2b(lo) | ((unsigned int)f2b(hi) << 16);
}

// ---- diagnostics ---------------------------------------------------------
__global__ __launch_bounds__(256)
void fill_r8(float* __restrict__ y, float code, int* __restrict__ flag) {
  const int i = blockIdx.x * 256 + threadIdx.x;
  y[i] = code;
  if (i == 0 && flag) *flag = 0;
}

__global__ __launch_bounds__(256)
void chk_r8(const u16* __restrict__ buf, int n, int code, int* __restrict__ flag) {
  __shared__ float sm[256];
  __shared__ int sn[256];
  float m = 0.f; int bad = 0;
  for (int i = threadIdx.x; i < n; i += 256) {
    const float v = b2f(buf[i]);
    if (v != v) bad = 1;
    const float a = fabsf(v);
    if (a > m) m = a;
  }
  sm[threadIdx.x] = m; sn[threadIdx.x] = bad;
  __syncthreads();
  for (int s = 128; s > 0; s >>= 1) {
    if (threadIdx.x < s) {
      sm[threadIdx.x] = fmaxf(sm[threadIdx.x], sm[threadIdx.x + s]);
      sn[threadIdx.x] |= sn[threadIdx.x + s];
    }
    __syncthreads();
  }
  if (threadIdx.x == 0)
    if (sn[0] || !(sm[0] > 1e-30f) || sm[0] > 1e4f) atomicCAS(flag, 0, code);
}

__global__ __launch_bounds__(256)
void stamp_r8(float* __restrict__ y, const int* __restrict__ flag) {
  const int f = *flag;
  if (f) y[blockIdx.x * 256 + threadIdx.x] = (float)f;
}

// =====================================================================
// Gather-GEMM, MFMA. Block = 128 rows x 128 cols, 4 waves (2x2), each wave
// 64x64 via 4x4 mfma_f32_16x16x32_bf16. LDS 16B-chunk XOR swizzle.
// SRCF=1: src is f32 rows (converted in-register while staging).
// EPI: 0 bf16 out; 1 bf16(acc*vmul); 2 f32 out.
// =====================================================================
template <int NTAPS, int EPI, int SRCF>
__global__ __launch_bounds__(256)
void gg_r8(const void* __restrict__ srcv, const u16* __restrict__ WT,
           const int* __restrict__ nbr, u16* __restrict__ outb,
           float* __restrict__ outf, const u16* __restrict__ vmul) {
  __shared__ uint4 sA[2048];   // 32 KB
  __shared__ uint4 sB[2048];   // 32 KB

  const int tid   = threadIdx.x;
  const int lane  = tid & 63;
  const int wave  = tid >> 6;
  const int wr    = wave >> 1, wc = wave & 1;
  const int lsub  = lane >> 4;
  const int lm    = lane & 15;
  const int row0  = blockIdx.x * 128;
  const int chunk = tid & 15;        // 16B chunk (8 bf16 elems)
  const int rbase = tid >> 4;        // 0..15

  f32x4 acc[4][4];
#pragma unroll
  for (int i = 0; i < 4; i++)
#pragma unroll
    for (int j = 0; j < 4; j++) acc[i][j] = (f32x4)(0.0f);

  int idx[8];
#pragma unroll
  for (int r = 0; r < 8; r++) {
    const int gr = row0 + r * 16 + rbase;
    idx[r] = nbr ? nbr[(size_t)gr * NTAPS] : gr;
  }

#pragma unroll 1
  for (int t = 0; t < NTAPS; ++t) {
    uint4 av[8], bv[8];
#pragma unroll
    for (int r = 0; r < 8; r++) {
      if (SRCF) {
        const float* s4 = (const float*)srcv + (size_t)idx[r] * C + chunk * 8;
        const float4 f0 = *(const float4*)s4;
        const float4 f1 = *(const float4*)(s4 + 4);
        av[r].x = pack2(f0.x, f0.y);
        av[r].y = pack2(f0.z, f0.w);
        av[r].z = pack2(f1.x, f1.y);
        av[r].w = pack2(f1.z, f1.w);
      } else {
        av[r] = *(const uint4*)((const u16*)srcv + (size_t)idx[r] * C + chunk * 8);
      }
    }
    const u16* wt = WT + (size_t)t * (C * C);
#pragma unroll
    for (int r = 0; r < 8; r++)
      bv[r] = *(const uint4*)(wt + (size_t)(r * 16 + rbase) * C + chunk * 8);
    if (t + 1 < NTAPS) {
#pragma unroll
      for (int r = 0; r < 8; r++) {
        const int gr = row0 + r * 16 + rbase;
        idx[r] = nbr ? nbr[(size_t)gr * NTAPS + (t + 1)] : gr;
      }
    }
    __syncthreads();   // prior iteration's LDS reads complete
#pragma unroll
    for (int r = 0; r < 8; r++) {
      const int row = r * 16 + rbase;
      sA[row * 16 + (chunk ^ (row & 7))] = av[r];
      sB[row * 16 + (chunk ^ (row & 7))] = bv[r];
    }
    __syncthreads();

#pragma unroll
    for (int s = 0; s < 4; s++) {
      bfrag af[4], bfr[4];
#pragma unroll
      for (int rt = 0; rt < 4; rt++) {
        const int row = wr * 64 + rt * 16 + lm;
        af[rt] = *(const bfrag*)&sA[row * 16 + ((s * 4 + lsub) ^ (row & 7))];
      }
#pragma unroll
      for (int ct = 0; ct < 4; ct++) {
        const int row = wc * 64 + ct * 16 + lm;
        bfr[ct] = *(const bfrag*)&sB[row * 16 + ((s * 4 + lsub) ^ (row & 7))];
      }
#pragma unroll
      for (int rt = 0; rt < 4; rt++)
#pragma unroll
        for (int ct = 0; ct < 4; ct++)
          acc[rt][ct] = __builtin_amdgcn_mfma_f32_16x16x32_bf16(
              af[rt], bfr[ct], acc[rt][ct], 0, 0, 0);
    }
  }

  // C/D: col = lane&15, row = quad*4 + reg.
#pragma unroll
  for (int rt = 0; rt < 4; rt++) {
    const int rowb = row0 + wr * 64 + rt * 16 + lsub * 4;
#pragma unroll
    for (int ct = 0; ct < 4; ct++) {
      const int c = wc * 64 + ct * 16 + lm;
#pragma unroll
      for (int reg = 0; reg < 4; reg++) {
        const size_t off = (size_t)(rowb + reg) * C + c;
        const float v = acc[rt][ct][reg];
        if (EPI == 0)      outb[off] = f2b(v);
        else if (EPI == 1) outb[off] = f2b(v * b2f(vmul[off]));
        else               outf[off] = v;
      }
    }
  }
}

// ---- weights: f32 [..,Cin,Cout] -> bf16 [..,Cout,Cin] --------------------
__global__ __launch_bounds__(256)
void wt_r8(const float* __restrict__ W5, const float* __restrict__ W31,
           const float* __restrict__ W32, const float* __restrict__ Wa1,
           const float* __restrict__ Wv1,
           u16* __restrict__ T5, u16* __restrict__ T31, u16* __restrict__ T32,
           u16* __restrict__ Ta1, u16* __restrict__ Tv1) {
  const int b = blockIdx.x;
  const float* w;
  u16* o;
  if (b < 125)       { w = W5  + (size_t)b * 16384;         o = T5  + (size_t)b * 16384; }
  else if (b < 152)  { w = W31 + (size_t)(b - 125) * 16384; o = T31 + (size_t)(b - 125) * 16384; }
  else if (b < 179)  { w = W32 + (size_t)(b - 152) * 16384; o = T32 + (size_t)(b - 152) * 16384; }
  else if (b == 179) { w = Wa1; o = Ta1; }
  else               { w = Wv1; o = Tv1; }
  __shared__ u16 tile[128 * 129];
  for (int i = threadIdx.x; i < C * C; i += 256)
    tile[(i & 127) * 129 + (i >> 7)] = f2b(w[i]);   // tile[co][ci] = W[ci][co]
  __syncthreads();
  for (int i = threadIdx.x; i < C * C; i += 256)
    o[i] = tile[(i >> 7) * 129 + (i & 127)];        // o[co][ci]
}

// ---- BN partials (f32 buffer): block b owns rows [b*128, +128) -----------
__global__ __launch_bounds__(256)
void bnp_r8(const float* __restrict__ t, float* __restrict__ psum,
            float* __restrict__ psq) {
  const int b = blockIdx.x;
  const int c = threadIdx.x & 127;
  const int h = threadIdx.x >> 7;
  const float* p = t + (size_t)(b * 128 + h * 64) * C + c;
  float s = 0.f, q = 0.f;
#pragma unroll 8
  for (int j = 0; j < 64; j++) {
    const float v = p[(size_t)j * C];
    s += v; q += v * v;
  }
  __shared__ float ls[256], lq[256];
  ls[threadIdx.x] = s; lq[threadIdx.x] = q;
  __syncthreads();
  if (h == 0) {
    psum[b * 128 + c] = ls[c] + ls[c + 128];
    psq[b * 128 + c]  = lq[c] + lq[c + 128];
  }
}

__global__ __launch_bounds__(128)
void bnfin_r8(const float* __restrict__ psum, const float* __restrict__ psq,
              const float* __restrict__ gamma, const float* __restrict__ beta,
              float* __restrict__ scale, float* __restrict__ shift,
              int* __restrict__ flag, int code) {
  const int c = threadIdx.x;
  float s = 0.f, q = 0.f;
  for (int b = 0; b < 256; b++) {
    s += psum[b * 128 + c];
    q += psq[b * 128 + c];
  }
  const float mean = s * (1.0f / NPTS);
  const float var  = q * (1.0f / NPTS) - mean * mean;
  const float sc   = rsqrtf(var + EPS) * gamma[c];
  const float sh   = beta[c] - mean * sc;
  scale[c] = sc; shift[c] = sh;
  if (!(fabsf(sc) < 1e6f) || !(fabsf(sh) < 1e6f)) atomicCAS(flag, 0, code);
}

// ---- ew1: o = t*sc+sh + x; res=bf16(o); h=bf16(relu o) -------------------
__global__ __launch_bounds__(256)
void ew1_r8(const float* __restrict__ t, const float* __restrict__ x,
            const float* __restrict__ scale, const float* __restrict__ shift,
            u16* __restrict__ res, u16* __restrict__ h) {
  const int i = blockIdx.x * 256 + threadIdx.x;
  const int c = i & 127;
  const float o = t[i] * scale[c] + shift[c] + x[i];
  res[i] = f2b(o);
  h[i] = f2b(o < 0.f ? 0.f : o);     // NaN-transparent
}

// ---- ew2: y = relu(t2*sc+sh + res) -> F32 d_out --------------------------
__global__ __launch_bounds__(256)
void ew2_r8(const float* __restrict__ t2, const u16* __restrict__ res,
            const float* __restrict__ scale, const float* __restrict__ shift,
            float* __restrict__ y) {
  const int i = blockIdx.x * 256 + threadIdx.x;
  const int c = i & 127;
  const float o = t2[i] * scale[c] + shift[c] + b2f(res[i]);
  y[i] = o < 0.f ? 0.f : o;
}

// =====================================================================
extern "C" void kernel_launch(void* const* d_in, const int* in_sizes, int n_in,
                              void* d_out, int out_size, void* d_ws, size_t ws_size,
                              hipStream_t stream) {
  float* yout = (float*)d_out;
  const dim3 B256(256);

  const int expect[13] = { NPTS * C, C * C, C * C, 125 * C * C, 27 * C * C,
                           27 * C * C, C, C, C, C, NPTS * 125, NPTS * 27, NPTS * 27 };
  float code = 0.f;
  if (n_in != 13 || out_size != NPTS * C) code = 5900.f;
  else
    for (int i = 0; i < 13; i++)
      if (in_sizes[i] != expect[i]) { code = 4000.f + 100.f * i; break; }
  const size_t NEEDED = 5931008u + 16777216u + 8388608u + 8388608u + 262144u + 4096u;
  if (code == 0.f && ws_size < NEEDED) code = 2000.f + (float)(ws_size >> 20);
  if (code != 0.f) {
    fill_r8<<<dim3((out_size + 255) / 256), B256, 0, stream>>>(yout, code, nullptr);
    return;
  }

  const float* x   = (const float*)d_in[0];
  const float* Wa1 = (const float*)d_in[1];
  const float* Wv1 = (const float*)d_in[2];
  const float* W5  = (const float*)d_in[3];
  const float* W31 = (const float*)d_in[4];
  const float* W32 = (const float*)d_in[5];
  const float* g1  = (const float*)d_in[6];
  const float* b1  = (const float*)d_in[7];
  const float* g2  = (const float*)d_in[8];
  const float* b2  = (const float*)d_in[9];
  const int* nbr5  = (const int*)d_in[10];
  const int* nbr3a = (const int*)d_in[11];
  const int* nbr3b = (const int*)d_in[12];

  // ---- workspace (~39.8 MB) ----
  char* w = (char*)d_ws;
  u16* WT5  = (u16*)w; w += 4096000;
  u16* WT31 = (u16*)w; w += 884736;
  u16* WT32 = (u16*)w; w += 884736;
  u16* WTa1 = (u16*)w; w += 32768;
  u16* WTv1 = (u16*)w; w += 32768;
  char* AV  = w;       w += 16777216;          // a | v ; later t/t2 (f32 16MB)
  u16*   a_b = (u16*)AV;
  u16*   v_b = (u16*)(AV + 8388608);
  float* tf  = (float*)AV;
  u16* g_b  = (u16*)w; w += 8388608;           // g ; later res (bf16)
  u16* h_b  = (u16*)w; w += 8388608;           // h
  float* psum = (float*)w; w += 131072;
  float* psq  = (float*)w; w += 131072;
  float* sc1  = (float*)w; w += 512;
  float* sh1  = (float*)w; w += 512;
  float* sc2  = (float*)w; w += 512;
  float* sh2  = (float*)w; w += 512;
  int*   flag = (int*)w;   w += 256;

  const dim3 GG(NPTS / 128), GBN(256), GEW(NPTS * C / 256);

  fill_r8<<<GEW, B256, 0, stream>>>(yout, 3000.f, flag);   // sentinel + flag=0
  wt_r8<<<dim3(181), B256, 0, stream>>>(W5, W31, W32, Wa1, Wv1,
                                        WT5, WT31, WT32, WTa1, WTv1);

  // a = x @ Wa1 ; v = x @ Wv1   (f32 src)
  gg_r8<1, 0, 1><<<GG, B256, 0, stream>>>(x, WTa1, nullptr, a_b, nullptr, nullptr);
  chk_r8<<<dim3(1), B256, 0, stream>>>(a_b, 65536, 1100, flag);
  gg_r8<1, 0, 1><<<GG, B256, 0, stream>>>(x, WTv1, nullptr, v_b, nullptr, nullptr);

  // g = gather125(a)@W5 * v
  gg_r8<125, 1, 0><<<GG, B256, 0, stream>>>(a_b, WT5, nbr5, g_b, nullptr, v_b);
  chk_r8<<<dim3(1), B256, 0, stream>>>(g_b, 65536, 1200, flag);

  // t = gather27(g)@W31 -> f32 over AV (a,v dead)
  gg_r8<27, 2, 0><<<GG, B256, 0, stream>>>(g_b, WT31, nbr3a, nullptr, tf, nullptr);
  bnp_r8<<<GBN, B256, 0, stream>>>(tf, psum, psq);
  bnfin_r8<<<dim3(1), dim3(128), 0, stream>>>(psum, psq, g1, b1, sc1, sh1, flag, 1500);
  ew1_r8<<<GEW, B256, 0, stream>>>(tf, x, sc1, sh1, g_b, h_b);   // res->g_b, h->h_b
  chk_r8<<<dim3(1), B256, 0, stream>>>(h_b, 65536, 1300, flag);

  // t2 = gather27(h)@W32 -> f32 over AV (t dead)
  gg_r8<27, 2, 0><<<GG, B256, 0, stream>>>(h_b, WT32, nbr3b, nullptr, tf, nullptr);
  bnp_r8<<<GBN, B256, 0, stream>>>(tf, psum, psq);
  bnfin_r8<<<dim3(1), dim3(128), 0, stream>>>(psum, psq, g2, b2, sc2, sh2, flag, 1600);
  ew2_r8<<<GEW, B256, 0, stream>>>(tf, g_b, sc2, sh2, yout);

  stamp_r8<<<GEW, B256, 0, stream>>>(yout, flag);
}

// Round 9
// 1635.111 us; speedup vs baseline: 1.0832x; 1.0832x over previous
//
#include <hip/hip_runtime.h>
#include <stdint.h>

// MinkFormerBlock on MI355X (gfx950). I/O: f32 in, f32 out (verified R8).
// R9: occupancy fix. gg tile 128x128 -> 64x128 (LDS 48 KB -> 3 blocks/CU,
// grid 512, 37% occupancy) + m97-style 2-barrier software pipeline
// (tap t+1 global loads issue before tap t MFMA).
//
//   wt:        WT* = bf16(W^T)  [tap][Cout][Cin]
//   gg<1,0,1>: a = x @ Wa1 ; v = x @ Wv1      (f32 src -> bf16 out)
//   gg<125,1>: g = gather(a,nbr5)@W5 * v      (bf16, fused gate)
//   gg<27,2>:  t = gather(g,nbr3a)@W31        (f32)
//   bn+fin -> sc1,sh1 ; ew1: res=bf16->g_b, h=bf16(relu)->h_b
//   gg<27,2>:  t2 = gather(h,nbr3b)@W32      (f32)
//   bn+fin -> sc2,sh2 ; ew2: d_out = relu(t2*sc+sh + res)  (f32)

#define NPTS 32768
#define C 128
#define EPS 1e-5f

typedef unsigned short u16;
using bfrag = __attribute__((ext_vector_type(8))) short;   // 8 bf16 = 4 VGPRs
using f32x4 = __attribute__((ext_vector_type(4))) float;

__device__ __forceinline__ float b2f(u16 u) {
  union { unsigned int i; float f; } x;
  x.i = ((unsigned int)u) << 16;
  return x.f;
}
__device__ __forceinline__ u16 f2b(float f) {
  union { float f; unsigned int i; } x;
  x.f = f;
  unsigned int r = x.i + 0x7FFFu + ((x.i >> 16) & 1u);   // RNE
  return (u16)(r >> 16);
}
__device__ __forceinline__ unsigned int pack2(float lo, float hi) {
  return (unsigned int)f2b(lo) | ((unsigned int)f2b(hi) << 16);
}

// =====================================================================
// Gather-GEMM. Block = 64 rows x 128 cols, 4 waves (2 row x 2 col), wave =
// 32x64 via 2x4 mfma_f32_16x16x32_bf16, K=128 in 4 steps.
// LDS: sA 16 KB + sB 32 KB = 48 KB -> 3 blocks/CU. 16B-chunk XOR swizzle.
// Pipeline: regs hold tap t; write LDS; prefetch tap t+1 to regs; MFMA(t).
// SRCF=1: src rows are f32 (packed to bf16 in-register).
// EPI: 0 bf16 out; 1 bf16(acc*vmul); 2 f32 out.
// =====================================================================
template <int NTAPS, int EPI, int SRCF>
__global__ __launch_bounds__(256)
void gg_kernel(const void* __restrict__ srcv, const u16* __restrict__ WT,
               const int* __restrict__ nbr, u16* __restrict__ outb,
               float* __restrict__ outf, const u16* __restrict__ vmul) {
  __shared__ uint4 sA[1024];   // 64 rows x 16 chunks x 16B
  __shared__ uint4 sB[2048];   // 128 rows x 16 chunks x 16B

  const int tid  = threadIdx.x;
  const int lane = tid & 63;
  const int wave = tid >> 6;
  const int wr   = wave >> 1, wc = wave & 1;
  const int lsub = lane >> 4, lm = lane & 15;
  const int row0 = blockIdx.x * 64;

  const int arow = tid >> 2;          // 0..63, 4 threads/row
  const int ach0 = (tid & 3) * 4;     // chunks ach0..ach0+3
  const int brow = tid >> 1;          // 0..127, 2 threads/row
  const int bch0 = (tid & 1) * 8;     // chunks bch0..bch0+7

  f32x4 acc[2][4];
#pragma unroll
  for (int i = 0; i < 2; i++)
#pragma unroll
    for (int j = 0; j < 4; j++) acc[i][j] = (f32x4)(0.0f);

  // ---- preload tap 0 into registers
  int idx = nbr ? nbr[(size_t)(row0 + arow) * NTAPS] : (row0 + arow);
  uint4 av[4], bv[8];
#pragma unroll
  for (int j = 0; j < 4; j++) {
    if (SRCF) {
      const float* s4 = (const float*)srcv + (size_t)idx * C + (ach0 + j) * 8;
      const float4 f0 = *(const float4*)s4;
      const float4 f1 = *(const float4*)(s4 + 4);
      av[j].x = pack2(f0.x, f0.y); av[j].y = pack2(f0.z, f0.w);
      av[j].z = pack2(f1.x, f1.y); av[j].w = pack2(f1.z, f1.w);
    } else {
      av[j] = *(const uint4*)((const u16*)srcv + (size_t)idx * C + (ach0 + j) * 8);
    }
  }
#pragma unroll
  for (int j = 0; j < 8; j++)
    bv[j] = *(const uint4*)(WT + (size_t)brow * C + (bch0 + j) * 8);

#pragma unroll 1
  for (int t = 0; t < NTAPS; ++t) {
    __syncthreads();   // previous tap's LDS reads complete
#pragma unroll
    for (int j = 0; j < 4; j++)
      sA[arow * 16 + ((ach0 + j) ^ (arow & 7))] = av[j];
#pragma unroll
    for (int j = 0; j < 8; j++)
      sB[brow * 16 + ((bch0 + j) ^ (brow & 7))] = bv[j];
    __syncthreads();

    // ---- prefetch tap t+1 (overlaps the MFMA below)
    if (t + 1 < NTAPS) {
      idx = nbr ? nbr[(size_t)(row0 + arow) * NTAPS + (t + 1)] : (row0 + arow);
#pragma unroll
      for (int j = 0; j < 4; j++) {
        if (SRCF) {
          const float* s4 = (const float*)srcv + (size_t)idx * C + (ach0 + j) * 8;
          const float4 f0 = *(const float4*)s4;
          const float4 f1 = *(const float4*)(s4 + 4);
          av[j].x = pack2(f0.x, f0.y); av[j].y = pack2(f0.z, f0.w);
          av[j].z = pack2(f1.x, f1.y); av[j].w = pack2(f1.z, f1.w);
        } else {
          av[j] = *(const uint4*)((const u16*)srcv + (size_t)idx * C + (ach0 + j) * 8);
        }
      }
      const u16* wt = WT + (size_t)(t + 1) * (C * C);
#pragma unroll
      for (int j = 0; j < 8; j++)
        bv[j] = *(const uint4*)(wt + (size_t)brow * C + (bch0 + j) * 8);
    }

    // ---- 4 k-steps of 32
#pragma unroll
    for (int s = 0; s < 4; s++) {
      bfrag af[2], bfr[4];
#pragma unroll
      for (int rt = 0; rt < 2; rt++) {
        const int row = wr * 32 + rt * 16 + lm;
        af[rt] = *(const bfrag*)&sA[row * 16 + ((s * 4 + lsub) ^ (row & 7))];
      }
#pragma unroll
      for (int ct = 0; ct < 4; ct++) {
        const int row = wc * 64 + ct * 16 + lm;
        bfr[ct] = *(const bfrag*)&sB[row * 16 + ((s * 4 + lsub) ^ (row & 7))];
      }
#pragma unroll
      for (int rt = 0; rt < 2; rt++)
#pragma unroll
        for (int ct = 0; ct < 4; ct++)
          acc[rt][ct] = __builtin_amdgcn_mfma_f32_16x16x32_bf16(
              af[rt], bfr[ct], acc[rt][ct], 0, 0, 0);
    }
  }

  // ---- epilogue. C/D: col = lane&15, row = quad*4 + reg.
#pragma unroll
  for (int rt = 0; rt < 2; rt++) {
    const int rowb = row0 + wr * 32 + rt * 16 + lsub * 4;
#pragma unroll
    for (int ct = 0; ct < 4; ct++) {
      const int c = wc * 64 + ct * 16 + lm;
#pragma unroll
      for (int reg = 0; reg < 4; reg++) {
        const size_t off = (size_t)(rowb + reg) * C + c;
        const float v = acc[rt][ct][reg];
        if (EPI == 0)      outb[off] = f2b(v);
        else if (EPI == 1) outb[off] = f2b(v * b2f(vmul[off]));
        else               outf[off] = v;
      }
    }
  }
}

// ---- weights: f32 [..,Cin,Cout] -> bf16 [..,Cout,Cin] --------------------
__global__ __launch_bounds__(256)
void wt_kernel(const float* __restrict__ W5, const float* __restrict__ W31,
               const float* __restrict__ W32, const float* __restrict__ Wa1,
               const float* __restrict__ Wv1,
               u16* __restrict__ T5, u16* __restrict__ T31, u16* __restrict__ T32,
               u16* __restrict__ Ta1, u16* __restrict__ Tv1) {
  const int b = blockIdx.x;
  const float* w;
  u16* o;
  if (b < 125)       { w = W5  + (size_t)b * 16384;         o = T5  + (size_t)b * 16384; }
  else if (b < 152)  { w = W31 + (size_t)(b - 125) * 16384; o = T31 + (size_t)(b - 125) * 16384; }
  else if (b < 179)  { w = W32 + (size_t)(b - 152) * 16384; o = T32 + (size_t)(b - 152) * 16384; }
  else if (b == 179) { w = Wa1; o = Ta1; }
  else               { w = Wv1; o = Tv1; }
  __shared__ u16 tile[128 * 129];
  for (int i = threadIdx.x; i < C * C; i += 256)
    tile[(i & 127) * 129 + (i >> 7)] = f2b(w[i]);
  __syncthreads();
  for (int i = threadIdx.x; i < C * C; i += 256)
    o[i] = tile[(i >> 7) * 129 + (i & 127)];
}

// ---- BN partials (f32): block b owns rows [b*128, +128) ------------------
__global__ __launch_bounds__(256)
void bnp_kernel(const float* __restrict__ t, float* __restrict__ psum,
                float* __restrict__ psq) {
  const int b = blockIdx.x;
  const int c = threadIdx.x & 127;
  const int h = threadIdx.x >> 7;
  const float* p = t + (size_t)(b * 128 + h * 64) * C + c;
  float s = 0.f, q = 0.f;
#pragma unroll 8
  for (int j = 0; j < 64; j++) {
    const float v = p[(size_t)j * C];
    s += v; q += v * v;
  }
  __shared__ float ls[256], lq[256];
  ls[threadIdx.x] = s; lq[threadIdx.x] = q;
  __syncthreads();
  if (h == 0) {
    psum[b * 128 + c] = ls[c] + ls[c + 128];
    psq[b * 128 + c]  = lq[c] + lq[c + 128];
  }
}

__global__ __launch_bounds__(128)
void bnfin_kernel(const float* __restrict__ psum, const float* __restrict__ psq,
                  const float* __restrict__ gamma, const float* __restrict__ beta,
                  float* __restrict__ scale, float* __restrict__ shift) {
  const int c = threadIdx.x;
  float s = 0.f, q = 0.f;
  for (int b = 0; b < 256; b++) {
    s += psum[b * 128 + c];
    q += psq[b * 128 + c];
  }
  const float mean = s * (1.0f / NPTS);
  const float var  = q * (1.0f / NPTS) - mean * mean;
  const float sc   = rsqrtf(var + EPS) * gamma[c];
  scale[c] = sc;
  shift[c] = beta[c] - mean * sc;
}

// ---- ew1: o = t*sc+sh + x; res=bf16(o); h=bf16(relu o) -------------------
__global__ __launch_bounds__(256)
void ew1_kernel(const float* __restrict__ t, const float* __restrict__ x,
                const float* __restrict__ scale, const float* __restrict__ shift,
                u16* __restrict__ res, u16* __restrict__ h) {
  const int i = blockIdx.x * 256 + threadIdx.x;
  const int c = i & 127;
  const float o = t[i] * scale[c] + shift[c] + x[i];
  res[i] = f2b(o);
  h[i] = f2b(o < 0.f ? 0.f : o);
}

// ---- ew2: y = relu(t2*sc+sh + res) -> f32 d_out --------------------------
__global__ __launch_bounds__(256)
void ew2_kernel(const float* __restrict__ t2, const u16* __restrict__ res,
                const float* __restrict__ scale, const float* __restrict__ shift,
                float* __restrict__ y) {
  const int i = blockIdx.x * 256 + threadIdx.x;
  const int c = i & 127;
  const float o = t2[i] * scale[c] + shift[c] + b2f(res[i]);
  y[i] = o < 0.f ? 0.f : o;
}

// =====================================================================
extern "C" void kernel_launch(void* const* d_in, const int* in_sizes, int n_in,
                              void* d_out, int out_size, void* d_ws, size_t ws_size,
                              hipStream_t stream) {
  (void)in_sizes; (void)n_in; (void)out_size; (void)ws_size;

  const float* x   = (const float*)d_in[0];
  const float* Wa1 = (const float*)d_in[1];
  const float* Wv1 = (const float*)d_in[2];
  const float* W5  = (const float*)d_in[3];
  const float* W31 = (const float*)d_in[4];
  const float* W32 = (const float*)d_in[5];
  const float* g1  = (const float*)d_in[6];
  const float* b1  = (const float*)d_in[7];
  const float* g2  = (const float*)d_in[8];
  const float* b2  = (const float*)d_in[9];
  const int* nbr5  = (const int*)d_in[10];
  const int* nbr3a = (const int*)d_in[11];
  const int* nbr3b = (const int*)d_in[12];

  // ---- workspace (~39.8 MB) ----
  char* w = (char*)d_ws;
  u16* WT5  = (u16*)w; w += 4096000;
  u16* WT31 = (u16*)w; w += 884736;
  u16* WT32 = (u16*)w; w += 884736;
  u16* WTa1 = (u16*)w; w += 32768;
  u16* WTv1 = (u16*)w; w += 32768;
  char* AV  = w;       w += 16777216;          // a | v ; later t/t2 (f32)
  u16*   a_b = (u16*)AV;
  u16*   v_b = (u16*)(AV + 8388608);
  float* tf  = (float*)AV;
  u16* g_b  = (u16*)w; w += 8388608;           // g ; later res (bf16)
  u16* h_b  = (u16*)w; w += 8388608;           // h
  float* psum = (float*)w; w += 131072;
  float* psq  = (float*)w; w += 131072;
  float* sc1  = (float*)w; w += 512;
  float* sh1  = (float*)w; w += 512;
  float* sc2  = (float*)w; w += 512;
  float* sh2  = (float*)w; w += 512;

  const dim3 B256(256), GG(NPTS / 64), GBN(256), GEW(NPTS * C / 256);
  float* yout = (float*)d_out;

  wt_kernel<<<dim3(181), B256, 0, stream>>>(W5, W31, W32, Wa1, Wv1,
                                            WT5, WT31, WT32, WTa1, WTv1);

  // a = x @ Wa1 ; v = x @ Wv1
  gg_kernel<1, 0, 1><<<GG, B256, 0, stream>>>(x, WTa1, nullptr, a_b, nullptr, nullptr);
  gg_kernel<1, 0, 1><<<GG, B256, 0, stream>>>(x, WTv1, nullptr, v_b, nullptr, nullptr);

  // g = gather125(a)@W5 * v
  gg_kernel<125, 1, 0><<<GG, B256, 0, stream>>>(a_b, WT5, nbr5, g_b, nullptr, v_b);

  // t = gather27(g)@W31 -> f32 over AV (a,v dead)
  gg_kernel<27, 2, 0><<<GG, B256, 0, stream>>>(g_b, WT31, nbr3a, nullptr, tf, nullptr);
  bnp_kernel<<<GBN, B256, 0, stream>>>(tf, psum, psq);
  bnfin_kernel<<<dim3(1), dim3(128), 0, stream>>>(psum, psq, g1, b1, sc1, sh1);
  ew1_kernel<<<GEW, B256, 0, stream>>>(tf, x, sc1, sh1, g_b, h_b);   // res->g_b, h->h_b

  // t2 = gather27(h)@W32 -> f32 over AV (t dead)
  gg_kernel<27, 2, 0><<<GG, B256, 0, stream>>>(h_b, WT32, nbr3b, nullptr, tf, nullptr);
  bnp_kernel<<<GBN, B256, 0, stream>>>(tf, psum, psq);
  bnfin_kernel<<<dim3(1), dim3(128), 0, stream>>>(psum, psq, g2, b2, sc2, sh2);
  ew2_kernel<<<GEW, B256, 0, stream>>>(tf, g_b, sc2, sh2, yout);
}

// Round 10
// 1322.928 us; speedup vs baseline: 1.3389x; 1.2360x over previous
//
#include <hip/hip_runtime.h>
#include <stdint.h>

// MinkFormerBlock on MI355X (gfx950). I/O: f32 in, f32 out (verified R8).
// R10: traffic-optimal tile + prefetch. gg tile back to 128x128 (B-weight
// fabric demand halves vs R9's 64-row tile: 2.0 -> 1.0 GB on gg125) while
// KEEPING R9's register-prefetch pipeline (tap t+1 loads issue before tap t
// MFMA, hiding gather latency that R8 exposed). Grid 256, 8 waves/CU.
//
//   wt:        WT* = bf16(W^T)  [tap][Cout][Cin]
//   gg<1,0,1>: a = x @ Wa1 ; v = x @ Wv1      (f32 src -> bf16 out)
//   gg<125,1>: g = gather(a,nbr5)@W5 * v      (bf16, fused gate)
//   gg<27,2>:  t = gather(g,nbr3a)@W31        (f32)
//   bn+fin -> sc1,sh1 ; ew1: res=bf16->g_b, h=bf16(relu)->h_b
//   gg<27,2>:  t2 = gather(h,nbr3b)@W32       (f32)
//   bn+fin -> sc2,sh2 ; ew2: d_out = relu(t2*sc+sh + res)  (f32)

#define NPTS 32768
#define C 128
#define EPS 1e-5f

typedef unsigned short u16;
using bfrag = __attribute__((ext_vector_type(8))) short;   // 8 bf16 = 4 VGPRs
using f32x4 = __attribute__((ext_vector_type(4))) float;

__device__ __forceinline__ float b2f(u16 u) {
  union { unsigned int i; float f; } x;
  x.i = ((unsigned int)u) << 16;
  return x.f;
}
__device__ __forceinline__ u16 f2b(float f) {
  union { float f; unsigned int i; } x;
  x.f = f;
  unsigned int r = x.i + 0x7FFFu + ((x.i >> 16) & 1u);   // RNE
  return (u16)(r >> 16);
}
__device__ __forceinline__ unsigned int pack2(float lo, float hi) {
  return (unsigned int)f2b(lo) | ((unsigned int)f2b(hi) << 16);
}

// =====================================================================
// Gather-GEMM. Block = 128 rows x 128 cols, 4 waves (2x2), wave = 64x64 via
// 4x4 mfma_f32_16x16x32_bf16, K=128 in 4 steps. LDS 64 KB (A 32 + B 32),
// 16B-chunk XOR swizzle. Register prefetch: tap t+1 global loads issue
// after the LDS commit of tap t, before tap t's MFMA block.
// SRCF=1: src rows are f32 (packed to bf16 in-register while staging).
// EPI: 0 bf16 out; 1 bf16(acc*vmul); 2 f32 out.
// =====================================================================
template <int NTAPS, int EPI, int SRCF>
__global__ __launch_bounds__(256)
void gg_kernel(const void* __restrict__ srcv, const u16* __restrict__ WT,
               const int* __restrict__ nbr, u16* __restrict__ outb,
               float* __restrict__ outf, const u16* __restrict__ vmul) {
  __shared__ uint4 sA[2048];   // 128 rows x 16 chunks x 16B = 32 KB
  __shared__ uint4 sB[2048];   // 32 KB

  const int tid  = threadIdx.x;
  const int lane = tid & 63;
  const int wave = tid >> 6;
  const int wr   = wave >> 1, wc = wave & 1;
  const int lsub = lane >> 4, lm = lane & 15;
  const int row0 = blockIdx.x * 128;

  const int srow = tid >> 1;          // 0..127, 2 threads/row (A and B)
  const int sch0 = (tid & 1) * 8;     // chunks sch0..sch0+7

  f32x4 acc[4][4];
#pragma unroll
  for (int i = 0; i < 4; i++)
#pragma unroll
    for (int j = 0; j < 4; j++) acc[i][j] = (f32x4)(0.0f);

  // ---- preload tap 0 into registers
  int idx = nbr ? nbr[(size_t)(row0 + srow) * NTAPS] : (row0 + srow);
  uint4 av[8], bv[8];
#pragma unroll
  for (int j = 0; j < 8; j++) {
    if (SRCF) {
      const float* s4 = (const float*)srcv + (size_t)idx * C + (sch0 + j) * 8;
      const float4 f0 = *(const float4*)s4;
      const float4 f1 = *(const float4*)(s4 + 4);
      av[j].x = pack2(f0.x, f0.y); av[j].y = pack2(f0.z, f0.w);
      av[j].z = pack2(f1.x, f1.y); av[j].w = pack2(f1.z, f1.w);
    } else {
      av[j] = *(const uint4*)((const u16*)srcv + (size_t)idx * C + (sch0 + j) * 8);
    }
  }
#pragma unroll
  for (int j = 0; j < 8; j++)
    bv[j] = *(const uint4*)(WT + (size_t)srow * C + (sch0 + j) * 8);

#pragma unroll 1
  for (int t = 0; t < NTAPS; ++t) {
    __syncthreads();   // previous tap's LDS reads complete
#pragma unroll
    for (int j = 0; j < 8; j++)
      sA[srow * 16 + ((sch0 + j) ^ (srow & 7))] = av[j];
#pragma unroll
    for (int j = 0; j < 8; j++)
      sB[srow * 16 + ((sch0 + j) ^ (srow & 7))] = bv[j];
    __syncthreads();

    // ---- prefetch tap t+1 (latency hides behind the MFMA block below)
    if (t + 1 < NTAPS) {
      idx = nbr ? nbr[(size_t)(row0 + srow) * NTAPS + (t + 1)] : (row0 + srow);
#pragma unroll
      for (int j = 0; j < 8; j++) {
        if (SRCF) {
          const float* s4 = (const float*)srcv + (size_t)idx * C + (sch0 + j) * 8;
          const float4 f0 = *(const float4*)s4;
          const float4 f1 = *(const float4*)(s4 + 4);
          av[j].x = pack2(f0.x, f0.y); av[j].y = pack2(f0.z, f0.w);
          av[j].z = pack2(f1.x, f1.y); av[j].w = pack2(f1.z, f1.w);
        } else {
          av[j] = *(const uint4*)((const u16*)srcv + (size_t)idx * C + (sch0 + j) * 8);
        }
      }
      const u16* wt = WT + (size_t)(t + 1) * (C * C);
#pragma unroll
      for (int j = 0; j < 8; j++)
        bv[j] = *(const uint4*)(wt + (size_t)srow * C + (sch0 + j) * 8);
    }

    // ---- 4 k-steps of 32
#pragma unroll
    for (int s = 0; s < 4; s++) {
      bfrag af[4], bfr[4];
#pragma unroll
      for (int rt = 0; rt < 4; rt++) {
        const int row = wr * 64 + rt * 16 + lm;
        af[rt] = *(const bfrag*)&sA[row * 16 + ((s * 4 + lsub) ^ (row & 7))];
      }
#pragma unroll
      for (int ct = 0; ct < 4; ct++) {
        const int row = wc * 64 + ct * 16 + lm;
        bfr[ct] = *(const bfrag*)&sB[row * 16 + ((s * 4 + lsub) ^ (row & 7))];
      }
#pragma unroll
      for (int rt = 0; rt < 4; rt++)
#pragma unroll
        for (int ct = 0; ct < 4; ct++)
          acc[rt][ct] = __builtin_amdgcn_mfma_f32_16x16x32_bf16(
              af[rt], bfr[ct], acc[rt][ct], 0, 0, 0);
    }
  }

  // ---- epilogue. C/D: col = lane&15, row = quad*4 + reg.
#pragma unroll
  for (int rt = 0; rt < 4; rt++) {
    const int rowb = row0 + wr * 64 + rt * 16 + lsub * 4;
#pragma unroll
    for (int ct = 0; ct < 4; ct++) {
      const int c = wc * 64 + ct * 16 + lm;
#pragma unroll
      for (int reg = 0; reg < 4; reg++) {
        const size_t off = (size_t)(rowb + reg) * C + c;
        const float v = acc[rt][ct][reg];
        if (EPI == 0)      outb[off] = f2b(v);
        else if (EPI == 1) outb[off] = f2b(v * b2f(vmul[off]));
        else               outf[off] = v;
      }
    }
  }
}

// ---- weights: f32 [..,Cin,Cout] -> bf16 [..,Cout,Cin] --------------------
__global__ __launch_bounds__(256)
void wt_kernel(const float* __restrict__ W5, const float* __restrict__ W31,
               const float* __restrict__ W32, const float* __restrict__ Wa1,
               const float* __restrict__ Wv1,
               u16* __restrict__ T5, u16* __restrict__ T31, u16* __restrict__ T32,
               u16* __restrict__ Ta1, u16* __restrict__ Tv1) {
  const int b = blockIdx.x;
  const float* w;
  u16* o;
  if (b < 125)       { w = W5  + (size_t)b * 16384;         o = T5  + (size_t)b * 16384; }
  else if (b < 152)  { w = W31 + (size_t)(b - 125) * 16384; o = T31 + (size_t)(b - 125) * 16384; }
  else if (b < 179)  { w = W32 + (size_t)(b - 152) * 16384; o = T32 + (size_t)(b - 152) * 16384; }
  else if (b == 179) { w = Wa1; o = Ta1; }
  else               { w = Wv1; o = Tv1; }
  __shared__ u16 tile[128 * 129];
  for (int i = threadIdx.x; i < C * C; i += 256)
    tile[(i & 127) * 129 + (i >> 7)] = f2b(w[i]);
  __syncthreads();
  for (int i = threadIdx.x; i < C * C; i += 256)
    o[i] = tile[(i >> 7) * 129 + (i & 127)];
}

// ---- BN partials (f32): block b owns rows [b*128, +128) ------------------
__global__ __launch_bounds__(256)
void bnp_kernel(const float* __restrict__ t, float* __restrict__ psum,
                float* __restrict__ psq) {
  const int b = blockIdx.x;
  const int c = threadIdx.x & 127;
  const int h = threadIdx.x >> 7;
  const float* p = t + (size_t)(b * 128 + h * 64) * C + c;
  float s = 0.f, q = 0.f;
#pragma unroll 8
  for (int j = 0; j < 64; j++) {
    const float v = p[(size_t)j * C];
    s += v; q += v * v;
  }
  __shared__ float ls[256], lq[256];
  ls[threadIdx.x] = s; lq[threadIdx.x] = q;
  __syncthreads();
  if (h == 0) {
    psum[b * 128 + c] = ls[c] + ls[c + 128];
    psq[b * 128 + c]  = lq[c] + lq[c + 128];
  }
}

__global__ __launch_bounds__(128)
void bnfin_kernel(const float* __restrict__ psum, const float* __restrict__ psq,
                  const float* __restrict__ gamma, const float* __restrict__ beta,
                  float* __restrict__ scale, float* __restrict__ shift) {
  const int c = threadIdx.x;
  float s = 0.f, q = 0.f;
  for (int b = 0; b < 256; b++) {
    s += psum[b * 128 + c];
    q += psq[b * 128 + c];
  }
  const float mean = s * (1.0f / NPTS);
  const float var  = q * (1.0f / NPTS) - mean * mean;
  const float sc   = rsqrtf(var + EPS) * gamma[c];
  scale[c] = sc;
  shift[c] = beta[c] - mean * sc;
}

// ---- ew1: o = t*sc+sh + x; res=bf16(o); h=bf16(relu o) -------------------
__global__ __launch_bounds__(256)
void ew1_kernel(const float* __restrict__ t, const float* __restrict__ x,
                const float* __restrict__ scale, const float* __restrict__ shift,
                u16* __restrict__ res, u16* __restrict__ h) {
  const int i = blockIdx.x * 256 + threadIdx.x;
  const int c = i & 127;
  const float o = t[i] * scale[c] + shift[c] + x[i];
  res[i] = f2b(o);
  h[i] = f2b(o < 0.f ? 0.f : o);
}

// ---- ew2: y = relu(t2*sc+sh + res) -> f32 d_out --------------------------
__global__ __launch_bounds__(256)
void ew2_kernel(const float* __restrict__ t2, const u16* __restrict__ res,
                const float* __restrict__ scale, const float* __restrict__ shift,
                float* __restrict__ y) {
  const int i = blockIdx.x * 256 + threadIdx.x;
  const int c = i & 127;
  const float o = t2[i] * scale[c] + shift[c] + b2f(res[i]);
  y[i] = o < 0.f ? 0.f : o;
}

// =====================================================================
extern "C" void kernel_launch(void* const* d_in, const int* in_sizes, int n_in,
                              void* d_out, int out_size, void* d_ws, size_t ws_size,
                              hipStream_t stream) {
  (void)in_sizes; (void)n_in; (void)out_size; (void)ws_size;

  const float* x   = (const float*)d_in[0];
  const float* Wa1 = (const float*)d_in[1];
  const float* Wv1 = (const float*)d_in[2];
  const float* W5  = (const float*)d_in[3];
  const float* W31 = (const float*)d_in[4];
  const float* W32 = (const float*)d_in[5];
  const float* g1  = (const float*)d_in[6];
  const float* b1  = (const float*)d_in[7];
  const float* g2  = (const float*)d_in[8];
  const float* b2  = (const float*)d_in[9];
  const int* nbr5  = (const int*)d_in[10];
  const int* nbr3a = (const int*)d_in[11];
  const int* nbr3b = (const int*)d_in[12];

  // ---- workspace (~39.8 MB) ----
  char* w = (char*)d_ws;
  u16* WT5  = (u16*)w; w += 4096000;
  u16* WT31 = (u16*)w; w += 884736;
  u16* WT32 = (u16*)w; w += 884736;
  u16* WTa1 = (u16*)w; w += 32768;
  u16* WTv1 = (u16*)w; w += 32768;
  char* AV  = w;       w += 16777216;          // a | v ; later t/t2 (f32)
  u16*   a_b = (u16*)AV;
  u16*   v_b = (u16*)(AV + 8388608);
  float* tf  = (float*)AV;
  u16* g_b  = (u16*)w; w += 8388608;           // g ; later res (bf16)
  u16* h_b  = (u16*)w; w += 8388608;           // h
  float* psum = (float*)w; w += 131072;
  float* psq  = (float*)w; w += 131072;
  float* sc1  = (float*)w; w += 512;
  float* sh1  = (float*)w; w += 512;
  float* sc2  = (float*)w; w += 512;
  float* sh2  = (float*)w; w += 512;

  const dim3 B256(256), GG(NPTS / 128), GBN(256), GEW(NPTS * C / 256);
  float* yout = (float*)d_out;

  wt_kernel<<<dim3(181), B256, 0, stream>>>(W5, W31, W32, Wa1, Wv1,
                                            WT5, WT31, WT32, WTa1, WTv1);

  // a = x @ Wa1 ; v = x @ Wv1
  gg_kernel<1, 0, 1><<<GG, B256, 0, stream>>>(x, WTa1, nullptr, a_b, nullptr, nullptr);
  gg_kernel<1, 0, 1><<<GG, B256, 0, stream>>>(x, WTv1, nullptr, v_b, nullptr, nullptr);

  // g = gather125(a)@W5 * v
  gg_kernel<125, 1, 0><<<GG, B256, 0, stream>>>(a_b, WT5, nbr5, g_b, nullptr, v_b);

  // t = gather27(g)@W31 -> f32 over AV (a,v dead)
  gg_kernel<27, 2, 0><<<GG, B256, 0, stream>>>(g_b, WT31, nbr3a, nullptr, tf, nullptr);
  bnp_kernel<<<GBN, B256, 0, stream>>>(tf, psum, psq);
  bnfin_kernel<<<dim3(1), dim3(128), 0, stream>>>(psum, psq, g1, b1, sc1, sh1);
  ew1_kernel<<<GEW, B256, 0, stream>>>(tf, x, sc1, sh1, g_b, h_b);   // res->g_b, h->h_b

  // t2 = gather27(h)@W32 -> f32 over AV (t dead)
  gg_kernel<27, 2, 0><<<GG, B256, 0, stream>>>(h_b, WT32, nbr3b, nullptr, tf, nullptr);
  bnp_kernel<<<GBN, B256, 0, stream>>>(tf, psum, psq);
  bnfin_kernel<<<dim3(1), dim3(128), 0, stream>>>(psum, psq, g2, b2, sc2, sh2);
  ew2_kernel<<<GEW, B256, 0, stream>>>(tf, g_b, sc2, sh2, yout);
}

// Round 11
// 1318.038 us; speedup vs baseline: 1.3438x; 1.0037x over previous
//
#include <hip/hip_runtime.h>
#include <stdint.h>

// MinkFormerBlock on MI355X (gfx950). I/O: f32 in, f32 out (verified R8).
// R11: kill the scratch spill. R10's counters showed WRITE_SIZE = 2.0 GB on
// gg125 = 64 KB x 256 blocks x 125 taps — the av/bv staging arrays were
// spilled to scratch by the compiler under bare __launch_bounds__(256)
// (VGPR_Count 96 is too low for 64 acc + 64 staging regs). Grid is 1
// block/CU anyway, so __launch_bounds__(256, 1) lifts the VGPR cap for
// free and keeps staging in registers. Everything else identical to R10.
//
//   wt:        WT* = bf16(W^T)  [tap][Cout][Cin]
//   gg<1,0,1>: a = x @ Wa1 ; v = x @ Wv1      (f32 src -> bf16 out)
//   gg<125,1>: g = gather(a,nbr5)@W5 * v      (bf16, fused gate)
//   gg<27,2>:  t = gather(g,nbr3a)@W31        (f32)
//   bn+fin -> sc1,sh1 ; ew1: res=bf16->g_b, h=bf16(relu)->h_b
//   gg<27,2>:  t2 = gather(h,nbr3b)@W32       (f32)
//   bn+fin -> sc2,sh2 ; ew2: d_out = relu(t2*sc+sh + res)  (f32)

#define NPTS 32768
#define C 128
#define EPS 1e-5f

typedef unsigned short u16;
using bfrag = __attribute__((ext_vector_type(8))) short;   // 8 bf16 = 4 VGPRs
using f32x4 = __attribute__((ext_vector_type(4))) float;

__device__ __forceinline__ float b2f(u16 u) {
  union { unsigned int i; float f; } x;
  x.i = ((unsigned int)u) << 16;
  return x.f;
}
__device__ __forceinline__ u16 f2b(float f) {
  union { float f; unsigned int i; } x;
  x.f = f;
  unsigned int r = x.i + 0x7FFFu + ((x.i >> 16) & 1u);   // RNE
  return (u16)(r >> 16);
}
__device__ __forceinline__ unsigned int pack2(float lo, float hi) {
  return (unsigned int)f2b(lo) | ((unsigned int)f2b(hi) << 16);
}

// =====================================================================
// Gather-GEMM. Block = 128 rows x 128 cols, 4 waves (2x2), wave = 64x64 via
// 4x4 mfma_f32_16x16x32_bf16, K=128 in 4 steps. LDS 64 KB (A 32 + B 32),
// 16B-chunk XOR swizzle. Register prefetch: tap t+1 global loads issue
// after the LDS commit of tap t, before tap t's MFMA block.
// __launch_bounds__(256, 1): grid == 1 block/CU, so allow full VGPR budget
// (prevents av/bv scratch spill — the R8-R10 hidden 2 GB/launch traffic).
// SRCF=1: src rows are f32 (packed to bf16 in-register while staging).
// EPI: 0 bf16 out; 1 bf16(acc*vmul); 2 f32 out.
// =====================================================================
template <int NTAPS, int EPI, int SRCF>
__global__ __launch_bounds__(256, 1)
void gg_kernel(const void* __restrict__ srcv, const u16* __restrict__ WT,
               const int* __restrict__ nbr, u16* __restrict__ outb,
               float* __restrict__ outf, const u16* __restrict__ vmul) {
  __shared__ uint4 sA[2048];   // 128 rows x 16 chunks x 16B = 32 KB
  __shared__ uint4 sB[2048];   // 32 KB

  const int tid  = threadIdx.x;
  const int lane = tid & 63;
  const int wave = tid >> 6;
  const int wr   = wave >> 1, wc = wave & 1;
  const int lsub = lane >> 4, lm = lane & 15;
  const int row0 = blockIdx.x * 128;

  const int srow = tid >> 1;          // 0..127, 2 threads/row (A and B)
  const int sch0 = (tid & 1) * 8;     // chunks sch0..sch0+7

  f32x4 acc[4][4];
#pragma unroll
  for (int i = 0; i < 4; i++)
#pragma unroll
    for (int j = 0; j < 4; j++) acc[i][j] = (f32x4)(0.0f);

  // ---- preload tap 0 into registers
  int idx = nbr ? nbr[(size_t)(row0 + srow) * NTAPS] : (row0 + srow);
  uint4 av[8], bv[8];
#pragma unroll
  for (int j = 0; j < 8; j++) {
    if (SRCF) {
      const float* s4 = (const float*)srcv + (size_t)idx * C + (sch0 + j) * 8;
      const float4 f0 = *(const float4*)s4;
      const float4 f1 = *(const float4*)(s4 + 4);
      av[j].x = pack2(f0.x, f0.y); av[j].y = pack2(f0.z, f0.w);
      av[j].z = pack2(f1.x, f1.y); av[j].w = pack2(f1.z, f1.w);
    } else {
      av[j] = *(const uint4*)((const u16*)srcv + (size_t)idx * C + (sch0 + j) * 8);
    }
  }
#pragma unroll
  for (int j = 0; j < 8; j++)
    bv[j] = *(const uint4*)(WT + (size_t)srow * C + (sch0 + j) * 8);

#pragma unroll 1
  for (int t = 0; t < NTAPS; ++t) {
    __syncthreads();   // previous tap's LDS reads complete
#pragma unroll
    for (int j = 0; j < 8; j++)
      sA[srow * 16 + ((sch0 + j) ^ (srow & 7))] = av[j];
#pragma unroll
    for (int j = 0; j < 8; j++)
      sB[srow * 16 + ((sch0 + j) ^ (srow & 7))] = bv[j];
    __syncthreads();

    // ---- prefetch tap t+1 (latency hides behind the MFMA block below)
    if (t + 1 < NTAPS) {
      idx = nbr ? nbr[(size_t)(row0 + srow) * NTAPS + (t + 1)] : (row0 + srow);
#pragma unroll
      for (int j = 0; j < 8; j++) {
        if (SRCF) {
          const float* s4 = (const float*)srcv + (size_t)idx * C + (sch0 + j) * 8;
          const float4 f0 = *(const float4*)s4;
          const float4 f1 = *(const float4*)(s4 + 4);
          av[j].x = pack2(f0.x, f0.y); av[j].y = pack2(f0.z, f0.w);
          av[j].z = pack2(f1.x, f1.y); av[j].w = pack2(f1.z, f1.w);
        } else {
          av[j] = *(const uint4*)((const u16*)srcv + (size_t)idx * C + (sch0 + j) * 8);
        }
      }
      const u16* wt = WT + (size_t)(t + 1) * (C * C);
#pragma unroll
      for (int j = 0; j < 8; j++)
        bv[j] = *(const uint4*)(wt + (size_t)srow * C + (sch0 + j) * 8);
    }

    // ---- 4 k-steps of 32
#pragma unroll
    for (int s = 0; s < 4; s++) {
      bfrag af[4], bfr[4];
#pragma unroll
      for (int rt = 0; rt < 4; rt++) {
        const int row = wr * 64 + rt * 16 + lm;
        af[rt] = *(const bfrag*)&sA[row * 16 + ((s * 4 + lsub) ^ (row & 7))];
      }
#pragma unroll
      for (int ct = 0; ct < 4; ct++) {
        const int row = wc * 64 + ct * 16 + lm;
        bfr[ct] = *(const bfrag*)&sB[row * 16 + ((s * 4 + lsub) ^ (row & 7))];
      }
#pragma unroll
      for (int rt = 0; rt < 4; rt++)
#pragma unroll
        for (int ct = 0; ct < 4; ct++)
          acc[rt][ct] = __builtin_amdgcn_mfma_f32_16x16x32_bf16(
              af[rt], bfr[ct], acc[rt][ct], 0, 0, 0);
    }
  }

  // ---- epilogue. C/D: col = lane&15, row = quad*4 + reg.
#pragma unroll
  for (int rt = 0; rt < 4; rt++) {
    const int rowb = row0 + wr * 64 + rt * 16 + lsub * 4;
#pragma unroll
    for (int ct = 0; ct < 4; ct++) {
      const int c = wc * 64 + ct * 16 + lm;
#pragma unroll
      for (int reg = 0; reg < 4; reg++) {
        const size_t off = (size_t)(rowb + reg) * C + c;
        const float v = acc[rt][ct][reg];
        if (EPI == 0)      outb[off] = f2b(v);
        else if (EPI == 1) outb[off] = f2b(v * b2f(vmul[off]));
        else               outf[off] = v;
      }
    }
  }
}

// ---- weights: f32 [..,Cin,Cout] -> bf16 [..,Cout,Cin] --------------------
__global__ __launch_bounds__(256)
void wt_kernel(const float* __restrict__ W5, const float* __restrict__ W31,
               const float* __restrict__ W32, const float* __restrict__ Wa1,
               const float* __restrict__ Wv1,
               u16* __restrict__ T5, u16* __restrict__ T31, u16* __restrict__ T32,
               u16* __restrict__ Ta1, u16* __restrict__ Tv1) {
  const int b = blockIdx.x;
  const float* w;
  u16* o;
  if (b < 125)       { w = W5  + (size_t)b * 16384;         o = T5  + (size_t)b * 16384; }
  else if (b < 152)  { w = W31 + (size_t)(b - 125) * 16384; o = T31 + (size_t)(b - 125) * 16384; }
  else if (b < 179)  { w = W32 + (size_t)(b - 152) * 16384; o = T32 + (size_t)(b - 152) * 16384; }
  else if (b == 179) { w = Wa1; o = Ta1; }
  else               { w = Wv1; o = Tv1; }
  __shared__ u16 tile[128 * 129];
  for (int i = threadIdx.x; i < C * C; i += 256)
    tile[(i & 127) * 129 + (i >> 7)] = f2b(w[i]);
  __syncthreads();
  for (int i = threadIdx.x; i < C * C; i += 256)
    o[i] = tile[(i >> 7) * 129 + (i & 127)];
}

// ---- BN partials (f32): block b owns rows [b*128, +128) ------------------
__global__ __launch_bounds__(256)
void bnp_kernel(const float* __restrict__ t, float* __restrict__ psum,
                float* __restrict__ psq) {
  const int b = blockIdx.x;
  const int c = threadIdx.x & 127;
  const int h = threadIdx.x >> 7;
  const float* p = t + (size_t)(b * 128 + h * 64) * C + c;
  float s = 0.f, q = 0.f;
#pragma unroll 8
  for (int j = 0; j < 64; j++) {
    const float v = p[(size_t)j * C];
    s += v; q += v * v;
  }
  __shared__ float ls[256], lq[256];
  ls[threadIdx.x] = s; lq[threadIdx.x] = q;
  __syncthreads();
  if (h == 0) {
    psum[b * 128 + c] = ls[c] + ls[c + 128];
    psq[b * 128 + c]  = lq[c] + lq[c + 128];
  }
}

__global__ __launch_bounds__(128)
void bnfin_kernel(const float* __restrict__ psum, const float* __restrict__ psq,
                  const float* __restrict__ gamma, const float* __restrict__ beta,
                  float* __restrict__ scale, float* __restrict__ shift) {
  const int c = threadIdx.x;
  float s = 0.f, q = 0.f;
  for (int b = 0; b < 256; b++) {
    s += psum[b * 128 + c];
    q += psq[b * 128 + c];
  }
  const float mean = s * (1.0f / NPTS);
  const float var  = q * (1.0f / NPTS) - mean * mean;
  const float sc   = rsqrtf(var + EPS) * gamma[c];
  scale[c] = sc;
  shift[c] = beta[c] - mean * sc;
}

// ---- ew1: o = t*sc+sh + x; res=bf16(o); h=bf16(relu o) -------------------
__global__ __launch_bounds__(256)
void ew1_kernel(const float* __restrict__ t, const float* __restrict__ x,
                const float* __restrict__ scale, const float* __restrict__ shift,
                u16* __restrict__ res, u16* __restrict__ h) {
  const int i = blockIdx.x * 256 + threadIdx.x;
  const int c = i & 127;
  const float o = t[i] * scale[c] + shift[c] + x[i];
  res[i] = f2b(o);
  h[i] = f2b(o < 0.f ? 0.f : o);
}

// ---- ew2: y = relu(t2*sc+sh + res) -> f32 d_out --------------------------
__global__ __launch_bounds__(256)
void ew2_kernel(const float* __restrict__ t2, const u16* __restrict__ res,
                const float* __restrict__ scale, const float* __restrict__ shift,
                float* __restrict__ y) {
  const int i = blockIdx.x * 256 + threadIdx.x;
  const int c = i & 127;
  const float o = t2[i] * scale[c] + shift[c] + b2f(res[i]);
  y[i] = o < 0.f ? 0.f : o;
}

// =====================================================================
extern "C" void kernel_launch(void* const* d_in, const int* in_sizes, int n_in,
                              void* d_out, int out_size, void* d_ws, size_t ws_size,
                              hipStream_t stream) {
  (void)in_sizes; (void)n_in; (void)out_size; (void)ws_size;

  const float* x   = (const float*)d_in[0];
  const float* Wa1 = (const float*)d_in[1];
  const float* Wv1 = (const float*)d_in[2];
  const float* W5  = (const float*)d_in[3];
  const float* W31 = (const float*)d_in[4];
  const float* W32 = (const float*)d_in[5];
  const float* g1  = (const float*)d_in[6];
  const float* b1  = (const float*)d_in[7];
  const float* g2  = (const float*)d_in[8];
  const float* b2  = (const float*)d_in[9];
  const int* nbr5  = (const int*)d_in[10];
  const int* nbr3a = (const int*)d_in[11];
  const int* nbr3b = (const int*)d_in[12];

  // ---- workspace (~39.8 MB) ----
  char* w = (char*)d_ws;
  u16* WT5  = (u16*)w; w += 4096000;
  u16* WT31 = (u16*)w; w += 884736;
  u16* WT32 = (u16*)w; w += 884736;
  u16* WTa1 = (u16*)w; w += 32768;
  u16* WTv1 = (u16*)w; w += 32768;
  char* AV  = w;       w += 16777216;          // a | v ; later t/t2 (f32)
  u16*   a_b = (u16*)AV;
  u16*   v_b = (u16*)(AV + 8388608);
  float* tf  = (float*)AV;
  u16* g_b  = (u16*)w; w += 8388608;           // g ; later res (bf16)
  u16* h_b  = (u16*)w; w += 8388608;           // h
  float* psum = (float*)w; w += 131072;
  float* psq  = (float*)w; w += 131072;
  float* sc1  = (float*)w; w += 512;
  float* sh1  = (float*)w; w += 512;
  float* sc2  = (float*)w; w += 512;
  float* sh2  = (float*)w; w += 512;

  const dim3 B256(256), GG(NPTS / 128), GBN(256), GEW(NPTS * C / 256);
  float* yout = (float*)d_out;

  wt_kernel<<<dim3(181), B256, 0, stream>>>(W5, W31, W32, Wa1, Wv1,
                                            WT5, WT31, WT32, WTa1, WTv1);

  // a = x @ Wa1 ; v = x @ Wv1
  gg_kernel<1, 0, 1><<<GG, B256, 0, stream>>>(x, WTa1, nullptr, a_b, nullptr, nullptr);
  gg_kernel<1, 0, 1><<<GG, B256, 0, stream>>>(x, WTv1, nullptr, v_b, nullptr, nullptr);

  // g = gather125(a)@W5 * v
  gg_kernel<125, 1, 0><<<GG, B256, 0, stream>>>(a_b, WT5, nbr5, g_b, nullptr, v_b);

  // t = gather27(g)@W31 -> f32 over AV (a,v dead)
  gg_kernel<27, 2, 0><<<GG, B256, 0, stream>>>(g_b, WT31, nbr3a, nullptr, tf, nullptr);
  bnp_kernel<<<GBN, B256, 0, stream>>>(tf, psum, psq);
  bnfin_kernel<<<dim3(1), dim3(128), 0, stream>>>(psum, psq, g1, b1, sc1, sh1);
  ew1_kernel<<<GEW, B256, 0, stream>>>(tf, x, sc1, sh1, g_b, h_b);   // res->g_b, h->h_b

  // t2 = gather27(h)@W32 -> f32 over AV (t dead)
  gg_kernel<27, 2, 0><<<GG, B256, 0, stream>>>(h_b, WT32, nbr3b, nullptr, tf, nullptr);
  bnp_kernel<<<GBN, B256, 0, stream>>>(tf, psum, psq);
  bnfin_kernel<<<dim3(1), dim3(128), 0, stream>>>(psum, psq, g2, b2, sc2, sh2);
  ew2_kernel<<<GEW, B256, 0, stream>>>(tf, g_b, sc2, sh2, yout);
}

// Round 12
// 527.448 us; speedup vs baseline: 3.3581x; 2.4989x over previous
//
#include <hip/hip_runtime.h>
#include <stdint.h>

// MinkFormerBlock on MI355X (gfx950). I/O: f32 in, f32 out (verified R8).
// R12: DMA staging. R10/R11 counters: WRITE_SIZE 2.0 GB == 64 KB x 256
// blocks x 125 taps (staging volume), VGPR_Count 96 (too low for 64 acc +
// 64 staging regs) -> the av/bv register staging was round-tripping through
// scratch, and __launch_bounds__ couldn't stop it. This round eliminates
// register staging entirely: __builtin_amdgcn_global_load_lds (16B/lane,
// async DMA) stages A (gathered rows, per-lane pointers) and B (weights)
// directly into LDS. Bank swizzle applied on the GLOBAL side (lane fetches
// chunk cs^(row&7) into linear LDS slot cs) since the LDS dest must be
// wave-uniform base + lane*16. m97 2-barrier loop per tap.
//
//   cvt:       xb = bf16(x)            (aliases h_b, dead until ew1)
//   wt:        WT* = bf16(W^T)  [tap][Cout][Cin]
//   gg<1,0>:   a = xb @ Wa1 ; v = xb @ Wv1     (bf16)
//   gg<125,1>: g = gather(a,nbr5)@W5 * v       (bf16, fused gate)
//   gg<27,2>:  t = gather(g,nbr3a)@W31         (f32)
//   bn+fin -> sc1,sh1 ; ew1: res=bf16->g_b, h=bf16(relu)->h_b
//   gg<27,2>:  t2 = gather(h,nbr3b)@W32        (f32)
//   bn+fin -> sc2,sh2 ; ew2: d_out = relu(t2*sc+sh + res)  (f32)

#define NPTS 32768
#define C 128
#define EPS 1e-5f

typedef unsigned short u16;
using bfrag = __attribute__((ext_vector_type(8))) short;   // 8 bf16 = 4 VGPRs
using f32x4 = __attribute__((ext_vector_type(4))) float;

__device__ __forceinline__ float b2f(u16 u) {
  union { unsigned int i; float f; } x;
  x.i = ((unsigned int)u) << 16;
  return x.f;
}
__device__ __forceinline__ u16 f2b(float f) {
  union { float f; unsigned int i; } x;
  x.f = f;
  unsigned int r = x.i + 0x7FFFu + ((x.i >> 16) & 1u);   // RNE
  return (u16)(r >> 16);
}

// async global->LDS, 16 B per lane; LDS dest is wave-uniform base + lane*16.
__device__ __forceinline__ void g2l16(const void* g, void* l) {
  __builtin_amdgcn_global_load_lds(
      (const __attribute__((address_space(1))) unsigned int*)g,
      (__attribute__((address_space(3))) unsigned int*)l,
      16, 0, 0);
}

// =====================================================================
// Gather-GEMM, DMA-staged. Block = 128 rows x 128 cols, 4 waves (2x2),
// wave = 64x64 via 4x4 mfma_f32_16x16x32_bf16, K=128 in 4 k-steps.
// LDS 64 KB (A 32 + B 32). Staging: wave w stages rows [w*32, w*32+32) of
// both tiles with 8 DMA instrs each (4 rows x 1024B per instr). Global-side
// XOR chunk swizzle: lane (r4=lane>>4, cs=lane&15) fetches global chunk
// cs^(row&7) of its row into linear LDS slot cs -> LDS[row][ch] holds
// global chunk ch^(row&7), so ds_read_b128 at ch=(s*4+quad)^(row&7) is
// conflict-benign (same layout as R8-R11).
// EPI: 0 bf16 out; 1 bf16(acc*vmul); 2 f32 out.
// =====================================================================
template <int NTAPS, int EPI>
__global__ __launch_bounds__(256)
void gg_kernel(const u16* __restrict__ src, const u16* __restrict__ WT,
               const int* __restrict__ nbr, u16* __restrict__ outb,
               float* __restrict__ outf, const u16* __restrict__ vmul) {
  __shared__ uint4 lds[4096];          // 64 KB: A [0,32K), B [32K,64K)
  char* sA = (char*)lds;
  char* sB = sA + 32768;

  const int tid  = threadIdx.x;
  const int lane = tid & 63;
  const int wave = tid >> 6;
  const int wr   = wave >> 1, wc = wave & 1;
  const int lsub = lane >> 4, lm = lane & 15;
  const int row0 = blockIdx.x * 128;
  const int r4   = lane >> 4;          // row within a DMA instr (0..3)
  const int cs   = lane & 15;          // chunk slot (0..15)

  f32x4 acc[4][4];
#pragma unroll
  for (int i = 0; i < 4; i++)
#pragma unroll
    for (int j = 0; j < 4; j++) acc[i][j] = (f32x4)(0.0f);

  // gather indices for tap 0: lane's row for DMA instr j is wave*32+j*4+r4
  int idx[8];
#pragma unroll
  for (int j = 0; j < 8; j++) {
    const int gr = row0 + wave * 32 + j * 4 + r4;
    idx[j] = nbr ? nbr[(size_t)gr * NTAPS] : gr;
  }

#pragma unroll 1
  for (int t = 0; t < NTAPS; ++t) {
    __syncthreads();   // prior tap's LDS reads complete
    // ---- A: 8 DMA instrs (gathered rows, global-side swizzle)
#pragma unroll
    for (int j = 0; j < 8; j++) {
      const int row = wave * 32 + j * 4 + r4;
      const char* gp = (const char*)src + ((size_t)idx[j] << 8) + ((cs ^ (row & 7)) << 4);
      g2l16(gp, sA + (wave * 32 + j * 4) * 256);
    }
    // ---- B: 8 DMA instrs (W[t]^T rows)
    const char* wt = (const char*)(WT + (size_t)t * (C * C));
#pragma unroll
    for (int j = 0; j < 8; j++) {
      const int row = wave * 32 + j * 4 + r4;
      const char* gp = wt + ((size_t)row << 8) + ((cs ^ (row & 7)) << 4);
      g2l16(gp, sB + (wave * 32 + j * 4) * 256);
    }
    // ---- prefetch next tap's indices (drained by the waitcnt below)
    if (t + 1 < NTAPS) {
#pragma unroll
      for (int j = 0; j < 8; j++) {
        const int gr = row0 + wave * 32 + j * 4 + r4;
        idx[j] = nbr ? nbr[(size_t)gr * NTAPS + (t + 1)] : gr;
      }
    }
    __builtin_amdgcn_s_waitcnt(0);   // drain DMA before barrier
    __syncthreads();                 // all waves' DMA visible

    // ---- 4 k-steps of 32
#pragma unroll
    for (int s = 0; s < 4; s++) {
      bfrag af[4], bfr[4];
#pragma unroll
      for (int rt = 0; rt < 4; rt++) {
        const int row = wr * 64 + rt * 16 + lm;
        af[rt] = *(const bfrag*)(sA + row * 256 + (((s * 4 + lsub) ^ (row & 7)) << 4));
      }
#pragma unroll
      for (int ct = 0; ct < 4; ct++) {
        const int row = wc * 64 + ct * 16 + lm;
        bfr[ct] = *(const bfrag*)(sB + row * 256 + (((s * 4 + lsub) ^ (row & 7)) << 4));
      }
#pragma unroll
      for (int rt = 0; rt < 4; rt++)
#pragma unroll
        for (int ct = 0; ct < 4; ct++)
          acc[rt][ct] = __builtin_amdgcn_mfma_f32_16x16x32_bf16(
              af[rt], bfr[ct], acc[rt][ct], 0, 0, 0);
    }
  }

  // ---- epilogue. C/D: col = lane&15, row = quad*4 + reg.
#pragma unroll
  for (int rt = 0; rt < 4; rt++) {
    const int rowb = row0 + wr * 64 + rt * 16 + lsub * 4;
#pragma unroll
    for (int ct = 0; ct < 4; ct++) {
      const int c = wc * 64 + ct * 16 + lm;
#pragma unroll
      for (int reg = 0; reg < 4; reg++) {
        const size_t off = (size_t)(rowb + reg) * C + c;
        const float v = acc[rt][ct][reg];
        if (EPI == 0)      outb[off] = f2b(v);
        else if (EPI == 1) outb[off] = f2b(v * b2f(vmul[off]));
        else               outf[off] = v;
      }
    }
  }
}

// ---- f32 -> bf16 bulk convert (for x) ------------------------------------
__global__ __launch_bounds__(256)
void cvt_kernel(const float* __restrict__ x, u16* __restrict__ xb) {
  const int i = (blockIdx.x * 256 + threadIdx.x) * 4;
  const float4 v = *(const float4*)(x + i);
  ushort4 o;
  o.x = f2b(v.x); o.y = f2b(v.y); o.z = f2b(v.z); o.w = f2b(v.w);
  *(ushort4*)(xb + i) = o;
}

// ---- weights: f32 [..,Cin,Cout] -> bf16 [..,Cout,Cin] --------------------
__global__ __launch_bounds__(256)
void wt_kernel(const float* __restrict__ W5, const float* __restrict__ W31,
               const float* __restrict__ W32, const float* __restrict__ Wa1,
               const float* __restrict__ Wv1,
               u16* __restrict__ T5, u16* __restrict__ T31, u16* __restrict__ T32,
               u16* __restrict__ Ta1, u16* __restrict__ Tv1) {
  const int b = blockIdx.x;
  const float* w;
  u16* o;
  if (b < 125)       { w = W5  + (size_t)b * 16384;         o = T5  + (size_t)b * 16384; }
  else if (b < 152)  { w = W31 + (size_t)(b - 125) * 16384; o = T31 + (size_t)(b - 125) * 16384; }
  else if (b < 179)  { w = W32 + (size_t)(b - 152) * 16384; o = T32 + (size_t)(b - 152) * 16384; }
  else if (b == 179) { w = Wa1; o = Ta1; }
  else               { w = Wv1; o = Tv1; }
  __shared__ u16 tile[128 * 129];
  for (int i = threadIdx.x; i < C * C; i += 256)
    tile[(i & 127) * 129 + (i >> 7)] = f2b(w[i]);
  __syncthreads();
  for (int i = threadIdx.x; i < C * C; i += 256)
    o[i] = tile[(i >> 7) * 129 + (i & 127)];
}

// ---- BN partials (f32): block b owns rows [b*128, +128) ------------------
__global__ __launch_bounds__(256)
void bnp_kernel(const float* __restrict__ t, float* __restrict__ psum,
                float* __restrict__ psq) {
  const int b = blockIdx.x;
  const int c = threadIdx.x & 127;
  const int h = threadIdx.x >> 7;
  const float* p = t + (size_t)(b * 128 + h * 64) * C + c;
  float s = 0.f, q = 0.f;
#pragma unroll 8
  for (int j = 0; j < 64; j++) {
    const float v = p[(size_t)j * C];
    s += v; q += v * v;
  }
  __shared__ float ls[256], lq[256];
  ls[threadIdx.x] = s; lq[threadIdx.x] = q;
  __syncthreads();
  if (h == 0) {
    psum[b * 128 + c] = ls[c] + ls[c + 128];
    psq[b * 128 + c]  = lq[c] + lq[c + 128];
  }
}

__global__ __launch_bounds__(128)
void bnfin_kernel(const float* __restrict__ psum, const float* __restrict__ psq,
                  const float* __restrict__ gamma, const float* __restrict__ beta,
                  float* __restrict__ scale, float* __restrict__ shift) {
  const int c = threadIdx.x;
  float s = 0.f, q = 0.f;
  for (int b = 0; b < 256; b++) {
    s += psum[b * 128 + c];
    q += psq[b * 128 + c];
  }
  const float mean = s * (1.0f / NPTS);
  const float var  = q * (1.0f / NPTS) - mean * mean;
  const float sc   = rsqrtf(var + EPS) * gamma[c];
  scale[c] = sc;
  shift[c] = beta[c] - mean * sc;
}

// ---- ew1: o = t*sc+sh + x; res=bf16(o); h=bf16(relu o) -------------------
__global__ __launch_bounds__(256)
void ew1_kernel(const float* __restrict__ t, const float* __restrict__ x,
                const float* __restrict__ scale, const float* __restrict__ shift,
                u16* __restrict__ res, u16* __restrict__ h) {
  const int i = blockIdx.x * 256 + threadIdx.x;
  const int c = i & 127;
  const float o = t[i] * scale[c] + shift[c] + x[i];
  res[i] = f2b(o);
  h[i] = f2b(o < 0.f ? 0.f : o);
}

// ---- ew2: y = relu(t2*sc+sh + res) -> f32 d_out --------------------------
__global__ __launch_bounds__(256)
void ew2_kernel(const float* __restrict__ t2, const u16* __restrict__ res,
                const float* __restrict__ scale, const float* __restrict__ shift,
                float* __restrict__ y) {
  const int i = blockIdx.x * 256 + threadIdx.x;
  const int c = i & 127;
  const float o = t2[i] * scale[c] + shift[c] + b2f(res[i]);
  y[i] = o < 0.f ? 0.f : o;
}

// =====================================================================
extern "C" void kernel_launch(void* const* d_in, const int* in_sizes, int n_in,
                              void* d_out, int out_size, void* d_ws, size_t ws_size,
                              hipStream_t stream) {
  (void)in_sizes; (void)n_in; (void)out_size; (void)ws_size;

  const float* x   = (const float*)d_in[0];
  const float* Wa1 = (const float*)d_in[1];
  const float* Wv1 = (const float*)d_in[2];
  const float* W5  = (const float*)d_in[3];
  const float* W31 = (const float*)d_in[4];
  const float* W32 = (const float*)d_in[5];
  const float* g1  = (const float*)d_in[6];
  const float* b1  = (const float*)d_in[7];
  const float* g2  = (const float*)d_in[8];
  const float* b2  = (const float*)d_in[9];
  const int* nbr5  = (const int*)d_in[10];
  const int* nbr3a = (const int*)d_in[11];
  const int* nbr3b = (const int*)d_in[12];

  // ---- workspace (~39.8 MB) ----
  char* w = (char*)d_ws;
  u16* WT5  = (u16*)w; w += 4096000;
  u16* WT31 = (u16*)w; w += 884736;
  u16* WT32 = (u16*)w; w += 884736;
  u16* WTa1 = (u16*)w; w += 32768;
  u16* WTv1 = (u16*)w; w += 32768;
  char* AV  = w;       w += 16777216;          // a | v ; later t/t2 (f32)
  u16*   a_b = (u16*)AV;
  u16*   v_b = (u16*)(AV + 8388608);
  float* tf  = (float*)AV;
  u16* g_b  = (u16*)w; w += 8388608;           // g ; later res (bf16)
  u16* h_b  = (u16*)w; w += 8388608;           // xb first, then h (bf16)
  u16* xb   = h_b;                             // alias: xb dead before ew1
  float* psum = (float*)w; w += 131072;
  float* psq  = (float*)w; w += 131072;
  float* sc1  = (float*)w; w += 512;
  float* sh1  = (float*)w; w += 512;
  float* sc2  = (float*)w; w += 512;
  float* sh2  = (float*)w; w += 512;

  const dim3 B256(256), GG(NPTS / 128), GBN(256), GEW(NPTS * C / 256);
  float* yout = (float*)d_out;

  cvt_kernel<<<dim3(NPTS * C / 1024), B256, 0, stream>>>(x, xb);
  wt_kernel<<<dim3(181), B256, 0, stream>>>(W5, W31, W32, Wa1, Wv1,
                                            WT5, WT31, WT32, WTa1, WTv1);

  // a = xb @ Wa1 ; v = xb @ Wv1
  gg_kernel<1, 0><<<GG, B256, 0, stream>>>(xb, WTa1, nullptr, a_b, nullptr, nullptr);
  gg_kernel<1, 0><<<GG, B256, 0, stream>>>(xb, WTv1, nullptr, v_b, nullptr, nullptr);

  // g = gather125(a)@W5 * v
  gg_kernel<125, 1><<<GG, B256, 0, stream>>>(a_b, WT5, nbr5, g_b, nullptr, v_b);

  // t = gather27(g)@W31 -> f32 over AV (a,v dead)
  gg_kernel<27, 2><<<GG, B256, 0, stream>>>(g_b, WT31, nbr3a, nullptr, tf, nullptr);
  bnp_kernel<<<GBN, B256, 0, stream>>>(tf, psum, psq);
  bnfin_kernel<<<dim3(1), dim3(128), 0, stream>>>(psum, psq, g1, b1, sc1, sh1);
  ew1_kernel<<<GEW, B256, 0, stream>>>(tf, x, sc1, sh1, g_b, h_b);   // res->g_b, h->h_b (xb dead)

  // t2 = gather27(h)@W32 -> f32 over AV (t dead)
  gg_kernel<27, 2><<<GG, B256, 0, stream>>>(h_b, WT32, nbr3b, nullptr, tf, nullptr);
  bnp_kernel<<<GBN, B256, 0, stream>>>(tf, psum, psq);
  bnfin_kernel<<<dim3(1), dim3(128), 0, stream>>>(psum, psq, g2, b2, sc2, sh2);
  ew2_kernel<<<GEW, B256, 0, stream>>>(tf, g_b, sc2, sh2, yout);
}

// Round 13
// 466.304 us; speedup vs baseline: 3.7984x; 1.1311x over previous
//
#include <hip/hip_runtime.h>
#include <stdint.h>

// MinkFormerBlock on MI355X (gfx950). I/O: f32 in, f32 out (verified R8).
// R13: double-buffered DMA staging. R12 (single-buffered global_load_lds)
// killed the scratch spill (WRITE 2GB->8MB, 830->266 us) but every tap
// serialized issue->drain->compute (MfmaUtil 20%). Now: LDS 128 KB, two
// {A,B} buffers; tap t+1's 16 DMA instrs issue BEFORE tap t's MFMA, so the
// drain (waitcnt before barrier) lands after ~700-1000 cyc of compute and
// the exposed stall is max(0, DMA - MFMA).
//
//   cvt:       xb = bf16(x)            (aliases h_b, dead until ew1)
//   wt:        WT* = bf16(W^T)  [tap][Cout][Cin]
//   gg<1,0>:   a = xb @ Wa1 ; v = xb @ Wv1     (bf16)
//   gg<125,1>: g = gather(a,nbr5)@W5 * v       (bf16, fused gate)
//   gg<27,2>:  t = gather(g,nbr3a)@W31         (f32)
//   bn+fin -> sc1,sh1 ; ew1: res=bf16->g_b, h=bf16(relu)->h_b
//   gg<27,2>:  t2 = gather(h,nbr3b)@W32        (f32)
//   bn+fin -> sc2,sh2 ; ew2: d_out = relu(t2*sc+sh + res)  (f32)

#define NPTS 32768
#define C 128
#define EPS 1e-5f

typedef unsigned short u16;
using bfrag = __attribute__((ext_vector_type(8))) short;   // 8 bf16 = 4 VGPRs
using f32x4 = __attribute__((ext_vector_type(4))) float;

__device__ __forceinline__ float b2f(u16 u) {
  union { unsigned int i; float f; } x;
  x.i = ((unsigned int)u) << 16;
  return x.f;
}
__device__ __forceinline__ u16 f2b(float f) {
  union { float f; unsigned int i; } x;
  x.f = f;
  unsigned int r = x.i + 0x7FFFu + ((x.i >> 16) & 1u);   // RNE
  return (u16)(r >> 16);
}

// async global->LDS, 16 B per lane; LDS dest is wave-uniform base + lane*16.
__device__ __forceinline__ void g2l16(const void* g, void* l) {
  __builtin_amdgcn_global_load_lds(
      (const __attribute__((address_space(1))) unsigned int*)g,
      (__attribute__((address_space(3))) unsigned int*)l,
      16, 0, 0);
}

// =====================================================================
// Gather-GEMM, double-buffered DMA. Block = 128x128, 4 waves (2x2), wave =
// 64x64 via 4x4 mfma_f32_16x16x32_bf16, K=128 in 4 k-steps.
// LDS 128 KB: buffer p at p*64KB, A [0,32K) B [32K,64K) within buffer.
// Staging: wave w stages rows [w*32,w*32+32) of A and B, 8 DMA instrs each
// (4 rows x 1024 B per instr). Global-side XOR chunk swizzle (lane r4,cs
// fetches global chunk cs^(row&7) into linear slot cs) so ds_read_b128 at
// ch=(s*4+quad)^(row&7) is conflict-benign. Per iter: issue DMA(t+1) ->
// MFMA(t) -> drain+barrier.
// EPI: 0 bf16 out; 1 bf16(acc*vmul); 2 f32 out.
// =====================================================================
template <int NTAPS, int EPI>
__global__ __launch_bounds__(256)
void gg_kernel(const u16* __restrict__ src, const u16* __restrict__ WT,
               const int* __restrict__ nbr, u16* __restrict__ outb,
               float* __restrict__ outf, const u16* __restrict__ vmul) {
  __shared__ uint4 lds[8192];          // 128 KB: two 64 KB buffers
  char* const base = (char*)lds;

  const int tid  = threadIdx.x;
  const int lane = tid & 63;
  const int wave = tid >> 6;
  const int wr   = wave >> 1, wc = wave & 1;
  const int lsub = lane >> 4, lm = lane & 15;
  const int row0 = blockIdx.x * 128;
  const int r4   = lane >> 4;          // row within a DMA instr (0..3)
  const int cs   = lane & 15;          // chunk slot (0..15)

  f32x4 acc[4][4];
#pragma unroll
  for (int i = 0; i < 4; i++)
#pragma unroll
    for (int j = 0; j < 4; j++) acc[i][j] = (f32x4)(0.0f);

  // ---- stage tap `idx`-rows + weights W[t] into buffer `buf`
  auto stage = [&](char* buf, const int* idx, int t) {
    char* sA = buf;
    char* sB = buf + 32768;
#pragma unroll
    for (int j = 0; j < 8; j++) {
      const int row = wave * 32 + j * 4 + r4;
      const char* gp = (const char*)src + ((size_t)idx[j] << 8) + ((cs ^ (row & 7)) << 4);
      g2l16(gp, sA + (wave * 32 + j * 4) * 256);
    }
    const char* wt = (const char*)(WT + (size_t)t * (C * C));
#pragma unroll
    for (int j = 0; j < 8; j++) {
      const int row = wave * 32 + j * 4 + r4;
      const char* gp = wt + ((size_t)row << 8) + ((cs ^ (row & 7)) << 4);
      g2l16(gp, sB + (wave * 32 + j * 4) * 256);
    }
  };

  // gather indices; lane's row for DMA instr j is wave*32 + j*4 + r4
  int idx[8];
#pragma unroll
  for (int j = 0; j < 8; j++) {
    const int gr = row0 + wave * 32 + j * 4 + r4;
    idx[j] = nbr ? nbr[(size_t)gr * NTAPS] : gr;
  }
  stage(base, idx, 0);                   // tap 0 -> buffer 0
  if (NTAPS > 1) {
#pragma unroll
    for (int j = 0; j < 8; j++) {        // indices for tap 1
      const int gr = row0 + wave * 32 + j * 4 + r4;
      idx[j] = nbr ? nbr[(size_t)gr * NTAPS + 1] : gr;
    }
  }
  __builtin_amdgcn_s_waitcnt(0);
  __syncthreads();

#pragma unroll 1
  for (int t = 0; t < NTAPS; ++t) {
    char* const cur = base + (size_t)(t & 1) * 65536;

    // ---- issue tap t+1 DMA into the other buffer (overlaps MFMA below)
    if (t + 1 < NTAPS) {
      stage(base + (size_t)((t + 1) & 1) * 65536, idx, t + 1);
      if (t + 2 < NTAPS) {
#pragma unroll
        for (int j = 0; j < 8; j++) {    // indices for tap t+2
          const int gr = row0 + wave * 32 + j * 4 + r4;
          idx[j] = nbr ? nbr[(size_t)gr * NTAPS + (t + 2)] : gr;
        }
      }
    }

    // ---- 4 k-steps of 32 on buffer cur
    char* const sA = cur;
    char* const sB = cur + 32768;
#pragma unroll
    for (int s = 0; s < 4; s++) {
      bfrag af[4], bfr[4];
#pragma unroll
      for (int rt = 0; rt < 4; rt++) {
        const int row = wr * 64 + rt * 16 + lm;
        af[rt] = *(const bfrag*)(sA + row * 256 + (((s * 4 + lsub) ^ (row & 7)) << 4));
      }
#pragma unroll
      for (int ct = 0; ct < 4; ct++) {
        const int row = wc * 64 + ct * 16 + lm;
        bfr[ct] = *(const bfrag*)(sB + row * 256 + (((s * 4 + lsub) ^ (row & 7)) << 4));
      }
#pragma unroll
      for (int rt = 0; rt < 4; rt++)
#pragma unroll
        for (int ct = 0; ct < 4; ct++)
          acc[rt][ct] = __builtin_amdgcn_mfma_f32_16x16x32_bf16(
              af[rt], bfr[ct], acc[rt][ct], 0, 0, 0);
    }

    __builtin_amdgcn_s_waitcnt(0);   // drain tap t+1 DMA (after compute)
    __syncthreads();
  }

  // ---- epilogue. C/D: col = lane&15, row = quad*4 + reg.
#pragma unroll
  for (int rt = 0; rt < 4; rt++) {
    const int rowb = row0 + wr * 64 + rt * 16 + lsub * 4;
#pragma unroll
    for (int ct = 0; ct < 4; ct++) {
      const int c = wc * 64 + ct * 16 + lm;
#pragma unroll
      for (int reg = 0; reg < 4; reg++) {
        const size_t off = (size_t)(rowb + reg) * C + c;
        const float v = acc[rt][ct][reg];
        if (EPI == 0)      outb[off] = f2b(v);
        else if (EPI == 1) outb[off] = f2b(v * b2f(vmul[off]));
        else               outf[off] = v;
      }
    }
  }
}

// ---- f32 -> bf16 bulk convert (for x) ------------------------------------
__global__ __launch_bounds__(256)
void cvt_kernel(const float* __restrict__ x, u16* __restrict__ xb) {
  const int i = (blockIdx.x * 256 + threadIdx.x) * 4;
  const float4 v = *(const float4*)(x + i);
  ushort4 o;
  o.x = f2b(v.x); o.y = f2b(v.y); o.z = f2b(v.z); o.w = f2b(v.w);
  *(ushort4*)(xb + i) = o;
}

// ---- weights: f32 [..,Cin,Cout] -> bf16 [..,Cout,Cin] --------------------
__global__ __launch_bounds__(256)
void wt_kernel(const float* __restrict__ W5, const float* __restrict__ W31,
               const float* __restrict__ W32, const float* __restrict__ Wa1,
               const float* __restrict__ Wv1,
               u16* __restrict__ T5, u16* __restrict__ T31, u16* __restrict__ T32,
               u16* __restrict__ Ta1, u16* __restrict__ Tv1) {
  const int b = blockIdx.x;
  const float* w;
  u16* o;
  if (b < 125)       { w = W5  + (size_t)b * 16384;         o = T5  + (size_t)b * 16384; }
  else if (b < 152)  { w = W31 + (size_t)(b - 125) * 16384; o = T31 + (size_t)(b - 125) * 16384; }
  else if (b < 179)  { w = W32 + (size_t)(b - 152) * 16384; o = T32 + (size_t)(b - 152) * 16384; }
  else if (b == 179) { w = Wa1; o = Ta1; }
  else               { w = Wv1; o = Tv1; }
  __shared__ u16 tile[128 * 129];
  for (int i = threadIdx.x; i < C * C; i += 256)
    tile[(i & 127) * 129 + (i >> 7)] = f2b(w[i]);
  __syncthreads();
  for (int i = threadIdx.x; i < C * C; i += 256)
    o[i] = tile[(i >> 7) * 129 + (i & 127)];
}

// ---- BN partials (f32): block b owns rows [b*128, +128) ------------------
__global__ __launch_bounds__(256)
void bnp_kernel(const float* __restrict__ t, float* __restrict__ psum,
                float* __restrict__ psq) {
  const int b = blockIdx.x;
  const int c = threadIdx.x & 127;
  const int h = threadIdx.x >> 7;
  const float* p = t + (size_t)(b * 128 + h * 64) * C + c;
  float s = 0.f, q = 0.f;
#pragma unroll 8
  for (int j = 0; j < 64; j++) {
    const float v = p[(size_t)j * C];
    s += v; q += v * v;
  }
  __shared__ float ls[256], lq[256];
  ls[threadIdx.x] = s; lq[threadIdx.x] = q;
  __syncthreads();
  if (h == 0) {
    psum[b * 128 + c] = ls[c] + ls[c + 128];
    psq[b * 128 + c]  = lq[c] + lq[c + 128];
  }
}

__global__ __launch_bounds__(128)
void bnfin_kernel(const float* __restrict__ psum, const float* __restrict__ psq,
                  const float* __restrict__ gamma, const float* __restrict__ beta,
                  float* __restrict__ scale, float* __restrict__ shift) {
  const int c = threadIdx.x;
  float s = 0.f, q = 0.f;
  for (int b = 0; b < 256; b++) {
    s += psum[b * 128 + c];
    q += psq[b * 128 + c];
  }
  const float mean = s * (1.0f / NPTS);
  const float var  = q * (1.0f / NPTS) - mean * mean;
  const float sc   = rsqrtf(var + EPS) * gamma[c];
  scale[c] = sc;
  shift[c] = beta[c] - mean * sc;
}

// ---- ew1: o = t*sc+sh + x; res=bf16(o); h=bf16(relu o) -------------------
__global__ __launch_bounds__(256)
void ew1_kernel(const float* __restrict__ t, const float* __restrict__ x,
                const float* __restrict__ scale, const float* __restrict__ shift,
                u16* __restrict__ res, u16* __restrict__ h) {
  const int i = blockIdx.x * 256 + threadIdx.x;
  const int c = i & 127;
  const float o = t[i] * scale[c] + shift[c] + x[i];
  res[i] = f2b(o);
  h[i] = f2b(o < 0.f ? 0.f : o);
}

// ---- ew2: y = relu(t2*sc+sh + res) -> f32 d_out --------------------------
__global__ __launch_bounds__(256)
void ew2_kernel(const float* __restrict__ t2, const u16* __restrict__ res,
                const float* __restrict__ scale, const float* __restrict__ shift,
                float* __restrict__ y) {
  const int i = blockIdx.x * 256 + threadIdx.x;
  const int c = i & 127;
  const float o = t2[i] * scale[c] + shift[c] + b2f(res[i]);
  y[i] = o < 0.f ? 0.f : o;
}

// =====================================================================
extern "C" void kernel_launch(void* const* d_in, const int* in_sizes, int n_in,
                              void* d_out, int out_size, void* d_ws, size_t ws_size,
                              hipStream_t stream) {
  (void)in_sizes; (void)n_in; (void)out_size; (void)ws_size;

  const float* x   = (const float*)d_in[0];
  const float* Wa1 = (const float*)d_in[1];
  const float* Wv1 = (const float*)d_in[2];
  const float* W5  = (const float*)d_in[3];
  const float* W31 = (const float*)d_in[4];
  const float* W32 = (const float*)d_in[5];
  const float* g1  = (const float*)d_in[6];
  const float* b1  = (const float*)d_in[7];
  const float* g2  = (const float*)d_in[8];
  const float* b2  = (const float*)d_in[9];
  const int* nbr5  = (const int*)d_in[10];
  const int* nbr3a = (const int*)d_in[11];
  const int* nbr3b = (const int*)d_in[12];

  // ---- workspace (~39.8 MB) ----
  char* w = (char*)d_ws;
  u16* WT5  = (u16*)w; w += 4096000;
  u16* WT31 = (u16*)w; w += 884736;
  u16* WT32 = (u16*)w; w += 884736;
  u16* WTa1 = (u16*)w; w += 32768;
  u16* WTv1 = (u16*)w; w += 32768;
  char* AV  = w;       w += 16777216;          // a | v ; later t/t2 (f32)
  u16*   a_b = (u16*)AV;
  u16*   v_b = (u16*)(AV + 8388608);
  float* tf  = (float*)AV;
  u16* g_b  = (u16*)w; w += 8388608;           // g ; later res (bf16)
  u16* h_b  = (u16*)w; w += 8388608;           // xb first, then h (bf16)
  u16* xb   = h_b;                             // alias: xb dead before ew1
  float* psum = (float*)w; w += 131072;
  float* psq  = (float*)w; w += 131072;
  float* sc1  = (float*)w; w += 512;
  float* sh1  = (float*)w; w += 512;
  float* sc2  = (float*)w; w += 512;
  float* sh2  = (float*)w; w += 512;

  const dim3 B256(256), GG(NPTS / 128), GBN(256), GEW(NPTS * C / 256);
  float* yout = (float*)d_out;

  cvt_kernel<<<dim3(NPTS * C / 1024), B256, 0, stream>>>(x, xb);
  wt_kernel<<<dim3(181), B256, 0, stream>>>(W5, W31, W32, Wa1, Wv1,
                                            WT5, WT31, WT32, WTa1, WTv1);

  // a = xb @ Wa1 ; v = xb @ Wv1
  gg_kernel<1, 0><<<GG, B256, 0, stream>>>(xb, WTa1, nullptr, a_b, nullptr, nullptr);
  gg_kernel<1, 0><<<GG, B256, 0, stream>>>(xb, WTv1, nullptr, v_b, nullptr, nullptr);

  // g = gather125(a)@W5 * v
  gg_kernel<125, 1><<<GG, B256, 0, stream>>>(a_b, WT5, nbr5, g_b, nullptr, v_b);

  // t = gather27(g)@W31 -> f32 over AV (a,v dead)
  gg_kernel<27, 2><<<GG, B256, 0, stream>>>(g_b, WT31, nbr3a, nullptr, tf, nullptr);
  bnp_kernel<<<GBN, B256, 0, stream>>>(tf, psum, psq);
  bnfin_kernel<<<dim3(1), dim3(128), 0, stream>>>(psum, psq, g1, b1, sc1, sh1);
  ew1_kernel<<<GEW, B256, 0, stream>>>(tf, x, sc1, sh1, g_b, h_b);   // res->g_b, h->h_b (xb dead)

  // t2 = gather27(h)@W32 -> f32 over AV (t dead)
  gg_kernel<27, 2><<<GG, B256, 0, stream>>>(h_b, WT32, nbr3b, nullptr, tf, nullptr);
  bnp_kernel<<<GBN, B256, 0, stream>>>(tf, psum, psq);
  bnfin_kernel<<<dim3(1), dim3(128), 0, stream>>>(psum, psq, g2, b2, sc2, sh2);
  ew2_kernel<<<GEW, B256, 0, stream>>>(tf, g_b, sc2, sh2, yout);
}